// Round 6
// baseline (193.924 us; speedup 1.0000x reference)
//
#include <hip/hip_runtime.h>

#define B_SZ   16
#define SEQ    2048
#define VOCAB  50257
#define EMBED  128
#define DSTATE 16
#define HID    256
#define NCLS   10
#define NEDGE  8192
#define KTR    64          // scan truncation: A<=0.55 -> A^64 < 2e-17
#define LN_EPS 1e-5f
#define NROW   (B_SZ*SEQ)  // 32768
#define BCAP   32          // bucket capacity per dst (Poisson lambda=4)
#define OVCAP  1024        // overflow fallback capacity

// k_prep phase block ranges
#define PB_CAST   4096                  // NROW*32/256
#define PB_BUCKET (PB_CAST + 512)       // B_SZ*NEDGE/256 = 512
#define PB_PRECM  (PB_BUCKET + 128)     // 256 hp, 2 per block
#define PB_CTAB   (PB_PRECM + 16)       // 16 d
#define PB_TOTAL  (PB_CTAB + 1)         // +1 precB

typedef float  f32x4 __attribute__((ext_vector_type(4)));
typedef short  s16x8 __attribute__((ext_vector_type(8)));

__device__ __forceinline__ float scrub(float x){
  return (x == x && fabsf(x) < 1e30f) ? x : 0.f;
}
// fp32 -> bf16 bits, round-to-nearest-even
__device__ __forceinline__ short f2b(float f){
  unsigned int u = __float_as_uint(f);
  unsigned int r = (u + 0x7fffu + ((u >> 16) & 1u)) >> 16;
  return (short)r;
}
__device__ __forceinline__ unsigned int pack2(float a, float b){
  return (unsigned int)(unsigned short)f2b(a)
       | ((unsigned int)(unsigned short)f2b(b) << 16);
}
__device__ __forceinline__ float lo2f(unsigned int v){ return __uint_as_float(v << 16); }
__device__ __forceinline__ float hi2f(unsigned int v){ return __uint_as_float(v & 0xffff0000u); }

// ---------------------------------------------------------------------------
// Heterogeneous prep kernel: all phases mutually independent. (round-0 exact)
__global__ __launch_bounds__(256) void k_prep(
    const int* __restrict__ tokens, const float* __restrict__ emb,
    const float* __restrict__ A_log, const float* __restrict__ B_w,
    const float* __restrict__ Wmsg, const float* __restrict__ Wupd,
    const int* __restrict__ edges,
    float* __restrict__ c_tab, short* __restrict__ Bf, float* __restrict__ MT,
    unsigned int* __restrict__ x_bf, int* __restrict__ cnt,
    unsigned short* __restrict__ bucket, int* __restrict__ ovf_cnt,
    int* __restrict__ ovf){
  int bid = blockIdx.x, tid = threadIdx.x;
  if (bid < PB_CAST){                            // ---- cast: 1,048,576 thr
    int gid = bid*256 + tid;                     // = NROW*32 exactly
    int row = gid >> 5, ch = gid & 31;
    int tok = tokens[row];
    tok = tok < 0 ? 0 : (tok >= VOCAB ? VOCAB-1 : tok);
    float4 v = *(const float4*)(emb + (size_t)tok*EMBED + ch*4);
    uint2 o; o.x = pack2(v.x, v.y); o.y = pack2(v.z, v.w);
    *(uint2*)(x_bf + (size_t)row*(EMBED/2) + ch*2) = o;
  } else if (bid < PB_BUCKET){                   // ---- bucket: 131,072 thr
    int eid = (bid-PB_CAST)*256 + tid;           // = B_SZ*NEDGE exactly
    int b = eid >> 13, i = eid & (NEDGE-1);
    const int* ei = edges + (size_t)b*2*NEDGE;
    int s = ei[i]         & (SEQ-1);
    int d = ei[NEDGE + i] & (SEQ-1);
    int gdst = (b << 11) | d;
    int slot = atomicAdd(&cnt[gdst], 1);
    if (slot < BCAP) bucket[(size_t)gdst*BCAP + slot] = (unsigned short)s;
    else {
      int o = atomicAdd(ovf_cnt, 1);
      if (o < OVCAP) ovf[o] = ((b << 11) | s) | (gdst << 16);
    }
  } else if (bid < PB_PRECM){                    // ---- precM: 2 hp per block
    int hp = (bid-PB_BUCKET)*2 + (tid >> 7);     // 0..255
    int e  = tid & 127;
    const float* w2 = Wupd + (size_t)hp*384 + 128;
    float acc = 0.f;
    for (int h1 = 0; h1 < HID; ++h1)
      acc += Wmsg[h1*EMBED + e] * w2[h1];
    MT[(size_t)hp*EMBED + e] = scrub(acc);
  } else if (bid < PB_CTAB){                     // ---- ctab (wave 0 only)
    if (tid < 64){
      int d = bid - PB_PRECM, lane = tid;        // d = 0..15
      float a0 = scrub(expf(-expf(A_log[(2*lane+0)*DSTATE + d])));
      float a1 = scrub(expf(-expf(A_log[(2*lane+1)*DSTATE + d])));
      float p0 = 1.f, p1 = 1.f;
      for (int k = 0; k < KTR; ++k){
        float s = p0 + p1;
        for (int off = 32; off; off >>= 1) s += __shfl_down(s, off);
        if (lane == 0) c_tab[k*DSTATE + d] = scrub(s * (1.0f/128.0f));
        p0 *= a0; p1 *= a1;
      }
    }
  } else {                                       // ---- precB (256 slots)
    int idx = tid;
    int c = idx >> 6, lane = idx & 63;
    int n = lane & 15;
    int kb = c*32 + (lane >> 4)*8;
    short v[8];
    #pragma unroll
    for (int jj = 0; jj < 8; ++jj) v[jj] = f2b(B_w[(size_t)n*EMBED + kb + jj]);
    *(s16x8*)(Bf + (size_t)idx*8) = *(s16x8*)v;
  }
}

// ---------------------------------------------------------------------------
// Fused bproj(MFMA) + conv + ssm + LayerNorm; b,m only in LDS. (round-0 exact)
//   blocks [0,512)   : 64 rows each (one batch, 64-row halo recomputed)
//   blocks [512,544) : precW — combined weight into B-fragment order
__global__ __launch_bounds__(256) void k_ssm_fused(
    const short* __restrict__ x_bf, const float* __restrict__ c_tab,
    const float* __restrict__ C_w, const float* __restrict__ D_skip,
    const float* __restrict__ ln_g, const float* __restrict__ ln_b,
    const short* __restrict__ Bf, const float* __restrict__ Wupd,
    const float* __restrict__ MT, unsigned int* __restrict__ h_out,
    short* __restrict__ Wcs){
  __shared__ float bsh[128][18];        // stride 18: 2-way (free) banking
  __shared__ float msh[64][18];
  __shared__ float Ct[DSTATE][EMBED+2];
  __shared__ float csh[KTR][DSTATE];
  int bid = blockIdx.x, tid = threadIdx.x;

  if (bid >= 512){                      // ---- precW rider blocks
    int idx = (bid-512)*256 + tid;      // 8192 fragment slots
    int c    = idx >> 10;
    int rem  = idx & 1023;
    int j    = rem >> 6;
    int lane = rem & 63;
    int n  = j*16 + (lane & 15);
    int kb = c*32 + (lane >> 4)*8;
    short v[8];
    #pragma unroll
    for (int jj = 0; jj < 8; ++jj){
      int k = kb + jj;
      float val = (k < 128) ? Wupd[(size_t)n*384 + k] : MT[(size_t)n*EMBED + (k-128)];
      v[jj] = f2b(val);
    }
    *(s16x8*)(Wcs + (size_t)idx*8) = *(s16x8*)v;
    return;
  }

  int b  = bid >> 5;
  int t0 = (bid & 31) * 64;
  for (int i = tid; i < DSTATE*EMBED; i += 256){
    int e = i >> 4, d = i & 15;         // coalesced read of C_w[e][d]
    Ct[d][e] = C_w[i];
  }
  for (int i = tid; i < KTR*DSTATE; i += 256)
    csh[i >> 4][i & 15] = c_tab[i];

  int wv = tid >> 6, lane = tid & 63;
  int m = lane & 15, lg = lane >> 4;

  // ---- bproj via MFMA: 8 tiles x 16 rows covering t0-64 .. t0+63
  const s16x8* Bp = (const s16x8*)Bf;
  #pragma unroll
  for (int tt = 0; tt < 2; ++tt){
    int tile = wv*2 + tt;               // 0..7
    int trow = t0 - 64 + tile*16;
    f32x4 acc = (f32x4){0.f,0.f,0.f,0.f};
    if (trow >= 0){
      const short* xrow = x_bf + ((size_t)(b*SEQ + trow + m))*EMBED + lg*8;
      #pragma unroll
      for (int c = 0; c < 4; ++c){
        s16x8 a = *(const s16x8*)(xrow + c*32);
        acc = __builtin_amdgcn_mfma_f32_16x16x32_bf16(a, Bp[c*64 + lane], acc, 0, 0, 0);
      }
    }
    // C/D: col = lane&15 (=d), row = lg*4 + r
    #pragma unroll
    for (int r = 0; r < 4; ++r)
      bsh[tile*16 + lg*4 + r][m] = scrub(acc[r]);
  }
  __syncthreads();

  // ---- conv from LDS (taps in csh, uniform-address broadcast)
  {
    int d = tid & 15;
    #pragma unroll
    for (int it = 0; it < 4; ++it){
      int q = (tid + it*256) >> 4;      // 0..63
      int t = t0 + q;
      int base = 64 + q;
      int kmax = (t+1 < KTR) ? t+1 : KTR;
      float acc = 0.f;
      for (int k = 0; k < kmax; ++k) acc += csh[k][d] * bsh[base-k][d];
      msh[q][d] = scrub(acc);
    }
  }
  __syncthreads();

  // ---- ssm + LN: each wave 16 rows; x from coalesced x_bf
  int e0 = lane*2;
  float2 dsk = *(const float2*)&D_skip[e0];
  float2 lgv = *(const float2*)&ln_g[e0];
  float2 lbv = *(const float2*)&ln_b[e0];
  const unsigned int* xb = (const unsigned int*)x_bf;
  for (int q = wv*16; q < wv*16+16; ++q){
    int row = b*SEQ + t0 + q;
    unsigned int xp = xb[(size_t)row*(EMBED/2) + lane];
    float x0 = lo2f(xp), x1 = hi2f(xp);
    float y0 = dsk.x*x0, y1 = dsk.y*x1;
    #pragma unroll
    for (int d = 0; d < DSTATE; ++d){
      float md = msh[q][d];             // wave-uniform -> LDS broadcast
      y0 += md * Ct[d][e0];
      y1 += md * Ct[d][e0+1];
    }
    y0 = scrub(y0); y1 = scrub(y1);
    float s = y0+y1, s2 = y0*y0 + y1*y1;
    for (int off = 32; off; off >>= 1){ s += __shfl_down(s,off); s2 += __shfl_down(s2,off); }
    s = __shfl(s, 0); s2 = __shfl(s2, 0);
    float mu  = s * (1.f/EMBED);
    float var = s2 * (1.f/EMBED) - mu*mu;
    float inv = rsqrtf(fmaxf(var, 0.f) + LN_EPS);
    float o0 = scrub(lgv.x*(y0-mu)*inv + lbv.x);
    float o1 = scrub(lgv.y*(y1-mu)*inv + lbv.y);
    h_out[(size_t)row*(EMBED/2) + lane] = pack2(o0, o1);
  }
}

// ---------------------------------------------------------------------------
// Fused back half: gather (wave-per-row, LDS-staged) + MFMA upd + relu +
// per-block psum + linear classifier epilogue (atomic adds into out).
// 16 rows/block, grid 2048 (8 blocks/CU); acc[4]/wave; NO launch-bounds min
// (round-1's failure was the (256,6) clamp -> VGPR 32 -> spills).
__global__ __launch_bounds__(256) void k_gupd(
    const short* __restrict__ h, const int* __restrict__ cnt,
    const unsigned short* __restrict__ bucket,
    const int* __restrict__ ovf_cnt, const int* __restrict__ ovf,
    const short* __restrict__ Wcs, const float* __restrict__ Wupd_b,
    const float* __restrict__ cls_w, const float* __restrict__ cls_b,
    float* __restrict__ out){
  __shared__ unsigned int gsh[16][68];   // padded g tile (b128-friendly)
  __shared__ float psum[HID];            // per-block pooled partials
  __shared__ float oacc[4][NCLS];        // per-wave class partials
  int tid = threadIdx.x;
  int wv = tid >> 6, lane = tid & 63;
  int row0 = blockIdx.x * 16;
  int b = row0 >> 11;                    // 16 | 2048: block is batch-pure
  int m = lane & 15, lg = lane >> 4;

  // ---- gather: each wave 4 rows, k_gather's proven coalesced pattern
  const unsigned int* hb  = (const unsigned int*)h + (size_t)b*SEQ*(EMBED/2);
  const unsigned int* h32 = (const unsigned int*)h;
  int on = *ovf_cnt; on = on > OVCAP ? OVCAP : on;   // ~always 0
  for (int i = 0; i < 4; ++i){
    int rloc = wv*4 + i;                 // 0..15
    int r = row0 + rloc;
    int n = cnt[r]; n = n > BCAP ? BCAP : n;
    const unsigned short* bk = bucket + (size_t)r*BCAP;
    float ax = 0.f, ay = 0.f;
    for (int t = 0; t < n; ++t){         // wave-uniform loop count
      unsigned int v = hb[(size_t)bk[t]*(EMBED/2) + lane];
      ax += lo2f(v); ay += hi2f(v);
    }
    for (int idx = 0; idx < on; ++idx){
      int pk = ovf[idx];
      if (((pk >> 16) & 0x7fff) == r){
        unsigned int v = h32[(size_t)(pk & 0xffff)*(EMBED/2) + lane];
        ax += lo2f(v); ay += hi2f(v);
      }
    }
    gsh[rloc][lane] = pack2(scrub(ax), scrub(ay));
  }
  __syncthreads();

  // ---- A-fragments: h from global (L2-hot), g from LDS (same bit path
  // as the old g_bf route: pack2 then fragment reinterpret)
  const short* hrow = h + (size_t)(row0+m)*EMBED + lg*8;
  s16x8 hfrag[4], gfrag[4];
  #pragma unroll
  for (int c = 0; c < 4; ++c){
    hfrag[c] = *(const s16x8*)(hrow + c*32);
    gfrag[c] = *(const s16x8*)&gsh[m][c*16 + lg*4];
  }

  // ---- MFMA: [h || g] @ Wcs^T; 4 waves split the 16 j-tiles (4 each)
  int j0 = wv*4;
  f32x4 acc[4];
  #pragma unroll
  for (int jj = 0; jj < 4; ++jj) acc[jj] = (f32x4){0.f,0.f,0.f,0.f};
  const s16x8* Bp = (const s16x8*)Wcs;
  #pragma unroll
  for (int c = 0; c < 8; ++c){
    s16x8 a = (c < 4) ? hfrag[c] : gfrag[c-4];
    #pragma unroll
    for (int jj = 0; jj < 4; ++jj){
      s16x8 bfr = Bp[(c*16 + j0 + jj)*64 + lane];
      acc[jj] = __builtin_amdgcn_mfma_f32_16x16x32_bf16(a, bfr, acc[jj], 0, 0, 0);
    }
  }

  // ---- relu + row-sum over this block's 16 rows -> psum[n] (disjoint n/wave)
  #pragma unroll
  for (int jj = 0; jj < 4; ++jj){
    int n = (j0 + jj)*16 + m;
    float bias = Wupd_b[n];
    float v = 0.f;
    #pragma unroll
    for (int r = 0; r < 4; ++r) v += fmaxf(acc[jj][r] + bias, 0.f);
    v += __shfl_down(v, 32);
    v += __shfl_down(v, 16);
    if (lane < 16) psum[n] = scrub(v);
  }
  __syncthreads();

  // ---- linear classifier epilogue: out[b][c] += (psum . cls_w[c]) / SEQ
  {
    float pn = psum[tid];                // tid = n, all 256 covered
    #pragma unroll
    for (int c = 0; c < NCLS; ++c){
      float t = pn * cls_w[c*HID + tid];
      for (int off = 32; off; off >>= 1) t += __shfl_down(t, off);
      if (lane == 0) oacc[wv][c] = t;
    }
    __syncthreads();
    if (tid < NCLS){
      float s = oacc[0][tid] + oacc[1][tid] + oacc[2][tid] + oacc[3][tid];
      atomicAdd(&out[b*NCLS + tid], scrub(s * (1.0f/SEQ)));
    }
    if ((blockIdx.x & 127) == 0 && tid < NCLS)     // once per batch: bias
      atomicAdd(&out[b*NCLS + tid], cls_b[tid]);
  }
}

// ---------------------------------------------------------------------------
extern "C" void kernel_launch(void* const* d_in, const int* in_sizes, int n_in,
                              void* d_out, int out_size, void* d_ws, size_t ws_size,
                              hipStream_t stream) {
  const int*   tokens = (const int*)d_in[0];
  const int*   edges  = (const int*)d_in[2];
  const float* emb    = (const float*)d_in[3];
  const float* A_log  = (const float*)d_in[4];
  const float* B_w    = (const float*)d_in[5];
  const float* C_w    = (const float*)d_in[6];
  const float* D_skip = (const float*)d_in[7];
  const float* ln_g   = (const float*)d_in[8];
  const float* ln_b   = (const float*)d_in[9];
  const float* Wmsg   = (const float*)d_in[10];
  const float* Wupd   = (const float*)d_in[11];
  const float* Wupd_b = (const float*)d_in[12];
  const float* cls_w  = (const float*)d_in[13];
  const float* cls_b  = (const float*)d_in[14];
  float* out = (float*)d_out;

  // workspace layout (~18.4 MB)
  char* ws = (char*)d_ws;
  float* c_tab = (float*)ws;  ws += 16*1024;                 // 4 KB used
  float* MT    = (float*)ws;  ws += (size_t)HID*EMBED*4;     // 128 KB
  short* Wcs   = (short*)ws;  ws += (size_t)HID*HID*2;       // 128 KB
  short* Bf    = (short*)ws;  ws += 16*1024;                 // 4 KB used
  char*  zbase = ws;
  int*   cnt   = (int*)ws;    ws += (size_t)NROW*4;          // 128 KB
  int*   ovf_cnt = (int*)ws;  ws += 64;
  int*   ovf   = (int*)ws;    ws += OVCAP*4;                 // 4 KB
  size_t zlen = (size_t)((char*)ws - zbase);
  unsigned short* bucket = (unsigned short*)ws; ws += (size_t)NROW*BCAP*2; // 2 MB
  short* x_bf  = (short*)ws;  ws += (size_t)NROW*EMBED*2;    // 8 MB
  short* h_bf  = (short*)ws;  ws += (size_t)NROW*EMBED*2;    // 8 MB

  hipMemsetAsync(zbase, 0, zlen, stream);
  hipMemsetAsync(out, 0, (size_t)B_SZ*NCLS*4, stream);
  hipLaunchKernelGGL(k_prep, dim3(PB_TOTAL), dim3(256), 0, stream,
                     tokens, emb, A_log, B_w, Wmsg, Wupd, edges,
                     c_tab, Bf, MT, (unsigned int*)x_bf, cnt, bucket, ovf_cnt, ovf);
  hipLaunchKernelGGL(k_ssm_fused, dim3(544), dim3(256), 0, stream,
                     x_bf, c_tab, C_w, D_skip, ln_g, ln_b, Bf, Wupd, MT,
                     (unsigned int*)h_bf, Wcs);
  hipLaunchKernelGGL(k_gupd, dim3(NROW/16), dim3(256), 0, stream,
                     h_bf, cnt, bucket, ovf_cnt, ovf, Wcs, Wupd_b,
                     cls_w, cls_b, out);
}

// Round 7
// 190.010 us; speedup vs baseline: 1.0206x; 1.0206x over previous
//
#include <hip/hip_runtime.h>

#define B_SZ   16
#define SEQ    2048
#define VOCAB  50257
#define EMBED  128
#define DSTATE 16
#define HID    256
#define NCLS   10
#define NEDGE  8192
#define KTR    64          // scan truncation: A<=0.55 -> A^64 < 2e-17
#define LN_EPS 1e-5f
#define NROW   (B_SZ*SEQ)  // 32768
#define BCAP   32          // bucket capacity per dst (Poisson lambda=4)
#define OVCAP  1024        // overflow fallback capacity

// k_prep phase block ranges
#define PB_CAST   4096                  // NROW*32/256
#define PB_BUCKET (PB_CAST + 512)       // B_SZ*NEDGE/256 = 512
#define PB_PRECM  (PB_BUCKET + 128)     // 256 hp, 2 per block
#define PB_CTAB   (PB_PRECM + 16)       // 16 d
#define PB_TOTAL  (PB_CTAB + 1)         // +1 precB

typedef float  f32x4 __attribute__((ext_vector_type(4)));
typedef short  s16x8 __attribute__((ext_vector_type(8)));

__device__ __forceinline__ float scrub(float x){
  return (x == x && fabsf(x) < 1e30f) ? x : 0.f;
}
// fp32 -> bf16 bits, round-to-nearest-even
__device__ __forceinline__ short f2b(float f){
  unsigned int u = __float_as_uint(f);
  unsigned int r = (u + 0x7fffu + ((u >> 16) & 1u)) >> 16;
  return (short)r;
}
__device__ __forceinline__ unsigned int pack2(float a, float b){
  return (unsigned int)(unsigned short)f2b(a)
       | ((unsigned int)(unsigned short)f2b(b) << 16);
}
__device__ __forceinline__ float lo2f(unsigned int v){ return __uint_as_float(v << 16); }
__device__ __forceinline__ float hi2f(unsigned int v){ return __uint_as_float(v & 0xffff0000u); }

// ---------------------------------------------------------------------------
// Heterogeneous prep kernel: all phases mutually independent. (round-0 exact)
__global__ __launch_bounds__(256) void k_prep(
    const int* __restrict__ tokens, const float* __restrict__ emb,
    const float* __restrict__ A_log, const float* __restrict__ B_w,
    const float* __restrict__ Wmsg, const float* __restrict__ Wupd,
    const int* __restrict__ edges,
    float* __restrict__ c_tab, short* __restrict__ Bf, float* __restrict__ MT,
    unsigned int* __restrict__ x_bf, int* __restrict__ cnt,
    unsigned short* __restrict__ bucket, int* __restrict__ ovf_cnt,
    int* __restrict__ ovf){
  int bid = blockIdx.x, tid = threadIdx.x;
  if (bid < PB_CAST){                            // ---- cast: 1,048,576 thr
    int gid = bid*256 + tid;                     // = NROW*32 exactly
    int row = gid >> 5, ch = gid & 31;
    int tok = tokens[row];
    tok = tok < 0 ? 0 : (tok >= VOCAB ? VOCAB-1 : tok);
    float4 v = *(const float4*)(emb + (size_t)tok*EMBED + ch*4);
    uint2 o; o.x = pack2(v.x, v.y); o.y = pack2(v.z, v.w);
    *(uint2*)(x_bf + (size_t)row*(EMBED/2) + ch*2) = o;
  } else if (bid < PB_BUCKET){                   // ---- bucket: 131,072 thr
    int eid = (bid-PB_CAST)*256 + tid;           // = B_SZ*NEDGE exactly
    int b = eid >> 13, i = eid & (NEDGE-1);
    const int* ei = edges + (size_t)b*2*NEDGE;
    int s = ei[i]         & (SEQ-1);
    int d = ei[NEDGE + i] & (SEQ-1);
    int gdst = (b << 11) | d;
    int slot = atomicAdd(&cnt[gdst], 1);
    if (slot < BCAP) bucket[(size_t)gdst*BCAP + slot] = (unsigned short)s;
    else {
      int o = atomicAdd(ovf_cnt, 1);
      if (o < OVCAP) ovf[o] = ((b << 11) | s) | (gdst << 16);
    }
  } else if (bid < PB_PRECM){                    // ---- precM: 2 hp per block
    int hp = (bid-PB_BUCKET)*2 + (tid >> 7);     // 0..255
    int e  = tid & 127;
    const float* w2 = Wupd + (size_t)hp*384 + 128;
    float acc = 0.f;
    for (int h1 = 0; h1 < HID; ++h1)
      acc += Wmsg[h1*EMBED + e] * w2[h1];
    MT[(size_t)hp*EMBED + e] = scrub(acc);
  } else if (bid < PB_CTAB){                     // ---- ctab (wave 0 only)
    if (tid < 64){
      int d = bid - PB_PRECM, lane = tid;        // d = 0..15
      float a0 = scrub(expf(-expf(A_log[(2*lane+0)*DSTATE + d])));
      float a1 = scrub(expf(-expf(A_log[(2*lane+1)*DSTATE + d])));
      float p0 = 1.f, p1 = 1.f;
      for (int k = 0; k < KTR; ++k){
        float s = p0 + p1;
        for (int off = 32; off; off >>= 1) s += __shfl_down(s, off);
        if (lane == 0) c_tab[k*DSTATE + d] = scrub(s * (1.0f/128.0f));
        p0 *= a0; p1 *= a1;
      }
    }
  } else {                                       // ---- precB (256 slots)
    int idx = tid;
    int c = idx >> 6, lane = idx & 63;
    int n = lane & 15;
    int kb = c*32 + (lane >> 4)*8;
    short v[8];
    #pragma unroll
    for (int jj = 0; jj < 8; ++jj) v[jj] = f2b(B_w[(size_t)n*EMBED + kb + jj]);
    *(s16x8*)(Bf + (size_t)idx*8) = *(s16x8*)v;
  }
}

// ---------------------------------------------------------------------------
// Fused bproj(MFMA) + conv + ssm + LayerNorm; b,m only in LDS. (round-0 exact)
//   blocks [0,512)   : 64 rows each (one batch, 64-row halo recomputed)
//   blocks [512,544) : precW — combined weight into B-fragment order
__global__ __launch_bounds__(256) void k_ssm_fused(
    const short* __restrict__ x_bf, const float* __restrict__ c_tab,
    const float* __restrict__ C_w, const float* __restrict__ D_skip,
    const float* __restrict__ ln_g, const float* __restrict__ ln_b,
    const short* __restrict__ Bf, const float* __restrict__ Wupd,
    const float* __restrict__ MT, unsigned int* __restrict__ h_out,
    short* __restrict__ Wcs){
  __shared__ float bsh[128][18];        // stride 18: 2-way (free) banking
  __shared__ float msh[64][18];
  __shared__ float Ct[DSTATE][EMBED+2];
  __shared__ float csh[KTR][DSTATE];
  int bid = blockIdx.x, tid = threadIdx.x;

  if (bid >= 512){                      // ---- precW rider blocks
    int idx = (bid-512)*256 + tid;      // 8192 fragment slots
    int c    = idx >> 10;
    int rem  = idx & 1023;
    int j    = rem >> 6;
    int lane = rem & 63;
    int n  = j*16 + (lane & 15);
    int kb = c*32 + (lane >> 4)*8;
    short v[8];
    #pragma unroll
    for (int jj = 0; jj < 8; ++jj){
      int k = kb + jj;
      float val = (k < 128) ? Wupd[(size_t)n*384 + k] : MT[(size_t)n*EMBED + (k-128)];
      v[jj] = f2b(val);
    }
    *(s16x8*)(Wcs + (size_t)idx*8) = *(s16x8*)v;
    return;
  }

  int b  = bid >> 5;
  int t0 = (bid & 31) * 64;
  for (int i = tid; i < DSTATE*EMBED; i += 256){
    int e = i >> 4, d = i & 15;         // coalesced read of C_w[e][d]
    Ct[d][e] = C_w[i];
  }
  for (int i = tid; i < KTR*DSTATE; i += 256)
    csh[i >> 4][i & 15] = c_tab[i];

  int wv = tid >> 6, lane = tid & 63;
  int m = lane & 15, lg = lane >> 4;

  // ---- bproj via MFMA: 8 tiles x 16 rows covering t0-64 .. t0+63
  const s16x8* Bp = (const s16x8*)Bf;
  #pragma unroll
  for (int tt = 0; tt < 2; ++tt){
    int tile = wv*2 + tt;               // 0..7
    int trow = t0 - 64 + tile*16;
    f32x4 acc = (f32x4){0.f,0.f,0.f,0.f};
    if (trow >= 0){
      const short* xrow = x_bf + ((size_t)(b*SEQ + trow + m))*EMBED + lg*8;
      #pragma unroll
      for (int c = 0; c < 4; ++c){
        s16x8 a = *(const s16x8*)(xrow + c*32);
        acc = __builtin_amdgcn_mfma_f32_16x16x32_bf16(a, Bp[c*64 + lane], acc, 0, 0, 0);
      }
    }
    // C/D: col = lane&15 (=d), row = lg*4 + r
    #pragma unroll
    for (int r = 0; r < 4; ++r)
      bsh[tile*16 + lg*4 + r][m] = scrub(acc[r]);
  }
  __syncthreads();

  // ---- conv from LDS (taps in csh, uniform-address broadcast)
  {
    int d = tid & 15;
    #pragma unroll
    for (int it = 0; it < 4; ++it){
      int q = (tid + it*256) >> 4;      // 0..63
      int t = t0 + q;
      int base = 64 + q;
      int kmax = (t+1 < KTR) ? t+1 : KTR;
      float acc = 0.f;
      for (int k = 0; k < kmax; ++k) acc += csh[k][d] * bsh[base-k][d];
      msh[q][d] = scrub(acc);
    }
  }
  __syncthreads();

  // ---- ssm + LN: each wave 16 rows; x from coalesced x_bf
  int e0 = lane*2;
  float2 dsk = *(const float2*)&D_skip[e0];
  float2 lgv = *(const float2*)&ln_g[e0];
  float2 lbv = *(const float2*)&ln_b[e0];
  const unsigned int* xb = (const unsigned int*)x_bf;
  for (int q = wv*16; q < wv*16+16; ++q){
    int row = b*SEQ + t0 + q;
    unsigned int xp = xb[(size_t)row*(EMBED/2) + lane];
    float x0 = lo2f(xp), x1 = hi2f(xp);
    float y0 = dsk.x*x0, y1 = dsk.y*x1;
    #pragma unroll
    for (int d = 0; d < DSTATE; ++d){
      float md = msh[q][d];             // wave-uniform -> LDS broadcast
      y0 += md * Ct[d][e0];
      y1 += md * Ct[d][e0+1];
    }
    y0 = scrub(y0); y1 = scrub(y1);
    float s = y0+y1, s2 = y0*y0 + y1*y1;
    for (int off = 32; off; off >>= 1){ s += __shfl_down(s,off); s2 += __shfl_down(s2,off); }
    s = __shfl(s, 0); s2 = __shfl(s2, 0);
    float mu  = s * (1.f/EMBED);
    float var = s2 * (1.f/EMBED) - mu*mu;
    float inv = rsqrtf(fmaxf(var, 0.f) + LN_EPS);
    float o0 = scrub(lgv.x*(y0-mu)*inv + lbv.x);
    float o1 = scrub(lgv.y*(y1-mu)*inv + lbv.y);
    h_out[(size_t)row*(EMBED/2) + lane] = pack2(o0, o1);
  }
}

// ---------------------------------------------------------------------------
// Fused back half: gather + MFMA upd + relu + psum + classifier epilogue.
// Round-6 structure; ONE change: ILP-batched gather. The round-6 counters
// showed 49us with all pipes idle at 38% occupancy -> latency-bound on the
// serial {bk[t] -> row load -> accumulate} chain. Batch 4 bucket indices
// per ushort4 load, issue the 4 independent 256B row loads back-to-back,
// then accumulate in original t-order (bit-identical sums).
__global__ __launch_bounds__(256) void k_gupd(
    const short* __restrict__ h, const int* __restrict__ cnt,
    const unsigned short* __restrict__ bucket,
    const int* __restrict__ ovf_cnt, const int* __restrict__ ovf,
    const short* __restrict__ Wcs, const float* __restrict__ Wupd_b,
    const float* __restrict__ cls_w, const float* __restrict__ cls_b,
    float* __restrict__ out){
  __shared__ unsigned int gsh[16][68];   // padded g tile (b128-friendly)
  __shared__ float psum[HID];            // per-block pooled partials
  __shared__ float oacc[4][NCLS];        // per-wave class partials
  int tid = threadIdx.x;
  int wv = tid >> 6, lane = tid & 63;
  int row0 = blockIdx.x * 16;
  int b = row0 >> 11;                    // 16 | 2048: block is batch-pure
  int m = lane & 15, lg = lane >> 4;

  // ---- gather: each wave 4 rows; 4-deep ILP batches
  const unsigned int* hb  = (const unsigned int*)h + (size_t)b*SEQ*(EMBED/2);
  const unsigned int* h32 = (const unsigned int*)h;
  int on = *ovf_cnt; on = on > OVCAP ? OVCAP : on;   // ~always 0
  for (int i = 0; i < 4; ++i){
    int rloc = wv*4 + i;                 // 0..15
    int r = row0 + rloc;
    int n = cnt[r]; n = n > BCAP ? BCAP : n;
    const unsigned short* bk = bucket + (size_t)r*BCAP;
    float ax = 0.f, ay = 0.f;
    int t = 0;
    for (; t + 4 <= n; t += 4){          // 4 independent loads in flight
      ushort4 s4 = *(const ushort4*)(bk + t);
      unsigned int v0 = hb[(size_t)s4.x*(EMBED/2) + lane];
      unsigned int v1 = hb[(size_t)s4.y*(EMBED/2) + lane];
      unsigned int v2 = hb[(size_t)s4.z*(EMBED/2) + lane];
      unsigned int v3 = hb[(size_t)s4.w*(EMBED/2) + lane];
      ax += lo2f(v0); ay += hi2f(v0);    // accumulate in original t-order
      ax += lo2f(v1); ay += hi2f(v1);
      ax += lo2f(v2); ay += hi2f(v2);
      ax += lo2f(v3); ay += hi2f(v3);
    }
    for (; t < n; ++t){                  // tail (<=3)
      unsigned int v = hb[(size_t)bk[t]*(EMBED/2) + lane];
      ax += lo2f(v); ay += hi2f(v);
    }
    for (int idx = 0; idx < on; ++idx){
      int pk = ovf[idx];
      if (((pk >> 16) & 0x7fff) == r){
        unsigned int v = h32[(size_t)(pk & 0xffff)*(EMBED/2) + lane];
        ax += lo2f(v); ay += hi2f(v);
      }
    }
    gsh[rloc][lane] = pack2(scrub(ax), scrub(ay));
  }
  __syncthreads();

  // ---- A-fragments: h from global (L2-hot), g from LDS (same bit path
  // as the old g_bf route: pack2 then fragment reinterpret)
  const short* hrow = h + (size_t)(row0+m)*EMBED + lg*8;
  s16x8 hfrag[4], gfrag[4];
  #pragma unroll
  for (int c = 0; c < 4; ++c){
    hfrag[c] = *(const s16x8*)(hrow + c*32);
    gfrag[c] = *(const s16x8*)&gsh[m][c*16 + lg*4];
  }

  // ---- MFMA: [h || g] @ Wcs^T; 4 waves split the 16 j-tiles (4 each)
  int j0 = wv*4;
  f32x4 acc[4];
  #pragma unroll
  for (int jj = 0; jj < 4; ++jj) acc[jj] = (f32x4){0.f,0.f,0.f,0.f};
  const s16x8* Bp = (const s16x8*)Wcs;
  #pragma unroll
  for (int c = 0; c < 8; ++c){
    s16x8 a = (c < 4) ? hfrag[c] : gfrag[c-4];
    #pragma unroll
    for (int jj = 0; jj < 4; ++jj){
      s16x8 bfr = Bp[(c*16 + j0 + jj)*64 + lane];
      acc[jj] = __builtin_amdgcn_mfma_f32_16x16x32_bf16(a, bfr, acc[jj], 0, 0, 0);
    }
  }

  // ---- relu + row-sum over this block's 16 rows -> psum[n] (disjoint n/wave)
  #pragma unroll
  for (int jj = 0; jj < 4; ++jj){
    int n = (j0 + jj)*16 + m;
    float bias = Wupd_b[n];
    float v = 0.f;
    #pragma unroll
    for (int r = 0; r < 4; ++r) v += fmaxf(acc[jj][r] + bias, 0.f);
    v += __shfl_down(v, 32);
    v += __shfl_down(v, 16);
    if (lane < 16) psum[n] = scrub(v);
  }
  __syncthreads();

  // ---- linear classifier epilogue: out[b][c] += (psum . cls_w[c]) / SEQ
  {
    float pn = psum[tid];                // tid = n, all 256 covered
    #pragma unroll
    for (int c = 0; c < NCLS; ++c){
      float t = pn * cls_w[c*HID + tid];
      for (int off = 32; off; off >>= 1) t += __shfl_down(t, off);
      if (lane == 0) oacc[wv][c] = t;
    }
    __syncthreads();
    if (tid < NCLS){
      float s = oacc[0][tid] + oacc[1][tid] + oacc[2][tid] + oacc[3][tid];
      atomicAdd(&out[b*NCLS + tid], scrub(s * (1.0f/SEQ)));
    }
    if ((blockIdx.x & 127) == 0 && tid < NCLS)     // once per batch: bias
      atomicAdd(&out[b*NCLS + tid], cls_b[tid]);
  }
}

// ---------------------------------------------------------------------------
extern "C" void kernel_launch(void* const* d_in, const int* in_sizes, int n_in,
                              void* d_out, int out_size, void* d_ws, size_t ws_size,
                              hipStream_t stream) {
  const int*   tokens = (const int*)d_in[0];
  const int*   edges  = (const int*)d_in[2];
  const float* emb    = (const float*)d_in[3];
  const float* A_log  = (const float*)d_in[4];
  const float* B_w    = (const float*)d_in[5];
  const float* C_w    = (const float*)d_in[6];
  const float* D_skip = (const float*)d_in[7];
  const float* ln_g   = (const float*)d_in[8];
  const float* ln_b   = (const float*)d_in[9];
  const float* Wmsg   = (const float*)d_in[10];
  const float* Wupd   = (const float*)d_in[11];
  const float* Wupd_b = (const float*)d_in[12];
  const float* cls_w  = (const float*)d_in[13];
  const float* cls_b  = (const float*)d_in[14];
  float* out = (float*)d_out;

  // workspace layout (~18.4 MB)
  char* ws = (char*)d_ws;
  float* c_tab = (float*)ws;  ws += 16*1024;                 // 4 KB used
  float* MT    = (float*)ws;  ws += (size_t)HID*EMBED*4;     // 128 KB
  short* Wcs   = (short*)ws;  ws += (size_t)HID*HID*2;       // 128 KB
  short* Bf    = (short*)ws;  ws += 16*1024;                 // 4 KB used
  char*  zbase = ws;
  int*   cnt   = (int*)ws;    ws += (size_t)NROW*4;          // 128 KB
  int*   ovf_cnt = (int*)ws;  ws += 64;
  int*   ovf   = (int*)ws;    ws += OVCAP*4;                 // 4 KB
  size_t zlen = (size_t)((char*)ws - zbase);
  unsigned short* bucket = (unsigned short*)ws; ws += (size_t)NROW*BCAP*2; // 2 MB
  short* x_bf  = (short*)ws;  ws += (size_t)NROW*EMBED*2;    // 8 MB
  short* h_bf  = (short*)ws;  ws += (size_t)NROW*EMBED*2;    // 8 MB

  hipMemsetAsync(zbase, 0, zlen, stream);
  hipMemsetAsync(out, 0, (size_t)B_SZ*NCLS*4, stream);
  hipLaunchKernelGGL(k_prep, dim3(PB_TOTAL), dim3(256), 0, stream,
                     tokens, emb, A_log, B_w, Wmsg, Wupd, edges,
                     c_tab, Bf, MT, (unsigned int*)x_bf, cnt, bucket, ovf_cnt, ovf);
  hipLaunchKernelGGL(k_ssm_fused, dim3(544), dim3(256), 0, stream,
                     x_bf, c_tab, C_w, D_skip, ln_g, ln_b, Bf, Wupd, MT,
                     (unsigned int*)h_bf, Wcs);
  hipLaunchKernelGGL(k_gupd, dim3(NROW/16), dim3(256), 0, stream,
                     h_bf, cnt, bucket, ovf_cnt, ovf, Wcs, Wupd_b,
                     cls_w, cls_b, out);
}

// Round 8
// 180.063 us; speedup vs baseline: 1.0770x; 1.0552x over previous
//
#include <hip/hip_runtime.h>

#define B_SZ   16
#define SEQ    2048
#define VOCAB  50257
#define EMBED  128
#define DSTATE 16
#define HID    256
#define NCLS   10
#define NEDGE  8192
#define KTR    64          // scan truncation: A<=0.55 -> A^64 < 2e-17
#define LN_EPS 1e-5f
#define NROW   (B_SZ*SEQ)  // 32768
#define BCAP   32          // bucket capacity per dst (Poisson lambda=4)
#define OVCAP  1024        // overflow fallback capacity

// k_prep phase block ranges (cast phase moved into k_ssm_fused)
#define PB_BUCKET 512                   // B_SZ*NEDGE/256 = 512
#define PB_PRECM  (PB_BUCKET + 128)     // 256 hp, 2 per block
#define PB_CTAB   (PB_PRECM + 16)       // 16 d
#define PB_TOTAL  (PB_CTAB + 1)         // +1 precB

typedef float  f32x4 __attribute__((ext_vector_type(4)));
typedef short  s16x8 __attribute__((ext_vector_type(8)));

__device__ __forceinline__ float scrub(float x){
  return (x == x && fabsf(x) < 1e30f) ? x : 0.f;
}
// fp32 -> bf16 bits, round-to-nearest-even
__device__ __forceinline__ short f2b(float f){
  unsigned int u = __float_as_uint(f);
  unsigned int r = (u + 0x7fffu + ((u >> 16) & 1u)) >> 16;
  return (short)r;
}
__device__ __forceinline__ unsigned int pack2(float a, float b){
  return (unsigned int)(unsigned short)f2b(a)
       | ((unsigned int)(unsigned short)f2b(b) << 16);
}
__device__ __forceinline__ float lo2f(unsigned int v){ return __uint_as_float(v << 16); }
__device__ __forceinline__ float hi2f(unsigned int v){ return __uint_as_float(v & 0xffff0000u); }

// ---------------------------------------------------------------------------
// Prep kernel (no cast phase anymore): bucket + precM + ctab + precB.
__global__ __launch_bounds__(256) void k_prep(
    const float* __restrict__ A_log, const float* __restrict__ B_w,
    const float* __restrict__ Wmsg, const float* __restrict__ Wupd,
    const int* __restrict__ edges,
    float* __restrict__ c_tab, short* __restrict__ Bf, float* __restrict__ MT,
    int* __restrict__ cnt, unsigned short* __restrict__ bucket,
    int* __restrict__ ovf_cnt, int* __restrict__ ovf){
  int bid = blockIdx.x, tid = threadIdx.x;
  if (bid < PB_BUCKET){                          // ---- bucket: 131,072 thr
    int eid = bid*256 + tid;                     // = B_SZ*NEDGE exactly
    int b = eid >> 13, i = eid & (NEDGE-1);
    const int* ei = edges + (size_t)b*2*NEDGE;
    int s = ei[i]         & (SEQ-1);
    int d = ei[NEDGE + i] & (SEQ-1);
    int gdst = (b << 11) | d;
    int slot = atomicAdd(&cnt[gdst], 1);
    if (slot < BCAP) bucket[(size_t)gdst*BCAP + slot] = (unsigned short)s;
    else {
      int o = atomicAdd(ovf_cnt, 1);
      if (o < OVCAP) ovf[o] = ((b << 11) | s) | (gdst << 16);
    }
  } else if (bid < PB_PRECM){                    // ---- precM: 2 hp per block
    int hp = (bid-PB_BUCKET)*2 + (tid >> 7);     // 0..255
    int e  = tid & 127;
    const float* w2 = Wupd + (size_t)hp*384 + 128;
    float acc = 0.f;
    for (int h1 = 0; h1 < HID; ++h1)
      acc += Wmsg[h1*EMBED + e] * w2[h1];
    MT[(size_t)hp*EMBED + e] = scrub(acc);
  } else if (bid < PB_CTAB){                     // ---- ctab (wave 0 only)
    if (tid < 64){
      int d = bid - PB_PRECM, lane = tid;        // d = 0..15
      float a0 = scrub(expf(-expf(A_log[(2*lane+0)*DSTATE + d])));
      float a1 = scrub(expf(-expf(A_log[(2*lane+1)*DSTATE + d])));
      float p0 = 1.f, p1 = 1.f;
      for (int k = 0; k < KTR; ++k){
        float s = p0 + p1;
        for (int off = 32; off; off >>= 1) s += __shfl_down(s, off);
        if (lane == 0) c_tab[k*DSTATE + d] = scrub(s * (1.0f/128.0f));
        p0 *= a0; p1 *= a1;
      }
    }
  } else {                                       // ---- precB (256 slots)
    int idx = tid;
    int c = idx >> 6, lane = idx & 63;
    int n = lane & 15;
    int kb = c*32 + (lane >> 4)*8;
    short v[8];
    #pragma unroll
    for (int jj = 0; jj < 8; ++jj) v[jj] = f2b(B_w[(size_t)n*EMBED + kb + jj]);
    *(s16x8*)(Bf + (size_t)idx*8) = *(s16x8*)v;
  }
}

// ---------------------------------------------------------------------------
// Fused emb-cast + bproj(MFMA) + conv + ssm + LayerNorm.
//   Cast fusion (round 8): each block gathers its own 128-row x-tile
//   (incl. 64-row halo) from emb directly into LDS — x_bf eliminated
//   (saves 8MB HBM write + 24MB re-read + the cast->ssm kernel boundary).
//   xsh stride 68 uints: 68 mod 32 = 4 -> 2-way (free) banking on both the
//   b128 fragment reads (rows vary) and the LN word reads (lanes vary).
//   blocks [0,512)   : 64 output rows each
//   blocks [512,544) : precW — combined weight into B-fragment order
__global__ __launch_bounds__(256) void k_ssm_fused(
    const int* __restrict__ tokens, const float* __restrict__ emb,
    const float* __restrict__ c_tab,
    const float* __restrict__ C_w, const float* __restrict__ D_skip,
    const float* __restrict__ ln_g, const float* __restrict__ ln_b,
    const short* __restrict__ Bf, const float* __restrict__ Wupd,
    const float* __restrict__ MT, unsigned int* __restrict__ h_out,
    short* __restrict__ Wcs){
  __shared__ unsigned int xsh[128][68]; // 34.8 KB x-tile (bf16 pairs)
  __shared__ float bsh[128][18];        // stride 18: 2-way (free) banking
  __shared__ float msh[64][18];
  __shared__ float Ct[DSTATE][EMBED+2];
  __shared__ float csh[KTR][DSTATE];
  int bid = blockIdx.x, tid = threadIdx.x;

  if (bid >= 512){                      // ---- precW rider blocks
    int idx = (bid-512)*256 + tid;      // 8192 fragment slots
    int c    = idx >> 10;
    int rem  = idx & 1023;
    int j    = rem >> 6;
    int lane = rem & 63;
    int n  = j*16 + (lane & 15);
    int kb = c*32 + (lane >> 4)*8;
    short v[8];
    #pragma unroll
    for (int jj = 0; jj < 8; ++jj){
      int k = kb + jj;
      float val = (k < 128) ? Wupd[(size_t)n*384 + k] : MT[(size_t)n*EMBED + (k-128)];
      v[jj] = f2b(val);
    }
    *(s16x8*)(Wcs + (size_t)idx*8) = *(s16x8*)v;
    return;
  }

  int b  = bid >> 5;
  int t0 = (bid & 31) * 64;

  // ---- emb gather -> LDS x-tile (bit-identical pack2 path to old k_prep)
  {
    const int* tkb = tokens + b*SEQ;
    for (int i = 0; i < 16; ++i){
      int gid = i*256 + tid;            // 4096 = 128 rows x 32 chunks
      int lr = gid >> 5, ch = gid & 31;
      int t = t0 - 64 + lr;
      uint2 o; o.x = 0u; o.y = 0u;
      if (t >= 0){
        int tok = tkb[t];
        tok = tok < 0 ? 0 : (tok >= VOCAB ? VOCAB-1 : tok);
        float4 v = *(const float4*)(emb + (size_t)tok*EMBED + ch*4);
        o.x = pack2(v.x, v.y); o.y = pack2(v.z, v.w);
      }
      *(uint2*)&xsh[lr][ch*2] = o;
    }
  }
  for (int i = tid; i < DSTATE*EMBED; i += 256){
    int e = i >> 4, d = i & 15;         // coalesced read of C_w[e][d]
    Ct[d][e] = C_w[i];
  }
  for (int i = tid; i < KTR*DSTATE; i += 256)
    csh[i >> 4][i & 15] = c_tab[i];
  __syncthreads();

  int wv = tid >> 6, lane = tid & 63;
  int m = lane & 15, lg = lane >> 4;

  // ---- bproj via MFMA: 8 tiles x 16 rows covering t0-64 .. t0+63 (from LDS)
  const s16x8* Bp = (const s16x8*)Bf;
  #pragma unroll
  for (int tt = 0; tt < 2; ++tt){
    int tile = wv*2 + tt;               // 0..7
    int trow = t0 - 64 + tile*16;
    f32x4 acc = (f32x4){0.f,0.f,0.f,0.f};
    if (trow >= 0){
      const short* xrow = (const short*)&xsh[tile*16 + m][0] + lg*8;
      #pragma unroll
      for (int c = 0; c < 4; ++c){
        s16x8 a = *(const s16x8*)(xrow + c*32);
        acc = __builtin_amdgcn_mfma_f32_16x16x32_bf16(a, Bp[c*64 + lane], acc, 0, 0, 0);
      }
    }
    // C/D: col = lane&15 (=d), row = lg*4 + r
    #pragma unroll
    for (int r = 0; r < 4; ++r)
      bsh[tile*16 + lg*4 + r][m] = scrub(acc[r]);
  }
  __syncthreads();

  // ---- conv from LDS (taps in csh, uniform-address broadcast)
  {
    int d = tid & 15;
    #pragma unroll
    for (int it = 0; it < 4; ++it){
      int q = (tid + it*256) >> 4;      // 0..63
      int t = t0 + q;
      int base = 64 + q;
      int kmax = (t+1 < KTR) ? t+1 : KTR;
      float acc = 0.f;
      for (int k = 0; k < kmax; ++k) acc += csh[k][d] * bsh[base-k][d];
      msh[q][d] = scrub(acc);
    }
  }
  __syncthreads();

  // ---- ssm + LN: each wave 16 rows; x from LDS tile
  int e0 = lane*2;
  float2 dsk = *(const float2*)&D_skip[e0];
  float2 lgv = *(const float2*)&ln_g[e0];
  float2 lbv = *(const float2*)&ln_b[e0];
  for (int q = wv*16; q < wv*16+16; ++q){
    int row = b*SEQ + t0 + q;
    unsigned int xp = xsh[64 + q][lane];
    float x0 = lo2f(xp), x1 = hi2f(xp);
    float y0 = dsk.x*x0, y1 = dsk.y*x1;
    #pragma unroll
    for (int d = 0; d < DSTATE; ++d){
      float md = msh[q][d];             // wave-uniform -> LDS broadcast
      y0 += md * Ct[d][e0];
      y1 += md * Ct[d][e0+1];
    }
    y0 = scrub(y0); y1 = scrub(y1);
    float s = y0+y1, s2 = y0*y0 + y1*y1;
    for (int off = 32; off; off >>= 1){ s += __shfl_down(s,off); s2 += __shfl_down(s2,off); }
    s = __shfl(s, 0); s2 = __shfl(s2, 0);
    float mu  = s * (1.f/EMBED);
    float var = s2 * (1.f/EMBED) - mu*mu;
    float inv = rsqrtf(fmaxf(var, 0.f) + LN_EPS);
    float o0 = scrub(lgv.x*(y0-mu)*inv + lbv.x);
    float o1 = scrub(lgv.y*(y1-mu)*inv + lbv.y);
    h_out[(size_t)row*(EMBED/2) + lane] = pack2(o0, o1);
  }
}

// ---------------------------------------------------------------------------
// Fused back half: gather + MFMA upd + relu + psum + classifier epilogue.
// (round-7 exact: ILP-batched gather, 16 rows/block, grid 2048)
__global__ __launch_bounds__(256) void k_gupd(
    const short* __restrict__ h, const int* __restrict__ cnt,
    const unsigned short* __restrict__ bucket,
    const int* __restrict__ ovf_cnt, const int* __restrict__ ovf,
    const short* __restrict__ Wcs, const float* __restrict__ Wupd_b,
    const float* __restrict__ cls_w, const float* __restrict__ cls_b,
    float* __restrict__ out){
  __shared__ unsigned int gsh[16][68];   // padded g tile (b128-friendly)
  __shared__ float psum[HID];            // per-block pooled partials
  __shared__ float oacc[4][NCLS];        // per-wave class partials
  int tid = threadIdx.x;
  int wv = tid >> 6, lane = tid & 63;
  int row0 = blockIdx.x * 16;
  int b = row0 >> 11;                    // 16 | 2048: block is batch-pure
  int m = lane & 15, lg = lane >> 4;

  // ---- gather: each wave 4 rows; 4-deep ILP batches
  const unsigned int* hb  = (const unsigned int*)h + (size_t)b*SEQ*(EMBED/2);
  const unsigned int* h32 = (const unsigned int*)h;
  int on = *ovf_cnt; on = on > OVCAP ? OVCAP : on;   // ~always 0
  for (int i = 0; i < 4; ++i){
    int rloc = wv*4 + i;                 // 0..15
    int r = row0 + rloc;
    int n = cnt[r]; n = n > BCAP ? BCAP : n;
    const unsigned short* bk = bucket + (size_t)r*BCAP;
    float ax = 0.f, ay = 0.f;
    int t = 0;
    for (; t + 4 <= n; t += 4){          // 4 independent loads in flight
      ushort4 s4 = *(const ushort4*)(bk + t);
      unsigned int v0 = hb[(size_t)s4.x*(EMBED/2) + lane];
      unsigned int v1 = hb[(size_t)s4.y*(EMBED/2) + lane];
      unsigned int v2 = hb[(size_t)s4.z*(EMBED/2) + lane];
      unsigned int v3 = hb[(size_t)s4.w*(EMBED/2) + lane];
      ax += lo2f(v0); ay += hi2f(v0);    // accumulate in original t-order
      ax += lo2f(v1); ay += hi2f(v1);
      ax += lo2f(v2); ay += hi2f(v2);
      ax += lo2f(v3); ay += hi2f(v3);
    }
    for (; t < n; ++t){                  // tail (<=3)
      unsigned int v = hb[(size_t)bk[t]*(EMBED/2) + lane];
      ax += lo2f(v); ay += hi2f(v);
    }
    for (int idx = 0; idx < on; ++idx){
      int pk = ovf[idx];
      if (((pk >> 16) & 0x7fff) == r){
        unsigned int v = h32[(size_t)(pk & 0xffff)*(EMBED/2) + lane];
        ax += lo2f(v); ay += hi2f(v);
      }
    }
    gsh[rloc][lane] = pack2(scrub(ax), scrub(ay));
  }
  __syncthreads();

  // ---- A-fragments: h from global (L2-hot), g from LDS (same bit path
  // as the old g_bf route: pack2 then fragment reinterpret)
  const short* hrow = h + (size_t)(row0+m)*EMBED + lg*8;
  s16x8 hfrag[4], gfrag[4];
  #pragma unroll
  for (int c = 0; c < 4; ++c){
    hfrag[c] = *(const s16x8*)(hrow + c*32);
    gfrag[c] = *(const s16x8*)&gsh[m][c*16 + lg*4];
  }

  // ---- MFMA: [h || g] @ Wcs^T; 4 waves split the 16 j-tiles (4 each)
  int j0 = wv*4;
  f32x4 acc[4];
  #pragma unroll
  for (int jj = 0; jj < 4; ++jj) acc[jj] = (f32x4){0.f,0.f,0.f,0.f};
  const s16x8* Bp = (const s16x8*)Wcs;
  #pragma unroll
  for (int c = 0; c < 8; ++c){
    s16x8 a = (c < 4) ? hfrag[c] : gfrag[c-4];
    #pragma unroll
    for (int jj = 0; jj < 4; ++jj){
      s16x8 bfr = Bp[(c*16 + j0 + jj)*64 + lane];
      acc[jj] = __builtin_amdgcn_mfma_f32_16x16x32_bf16(a, bfr, acc[jj], 0, 0, 0);
    }
  }

  // ---- relu + row-sum over this block's 16 rows -> psum[n] (disjoint n/wave)
  #pragma unroll
  for (int jj = 0; jj < 4; ++jj){
    int n = (j0 + jj)*16 + m;
    float bias = Wupd_b[n];
    float v = 0.f;
    #pragma unroll
    for (int r = 0; r < 4; ++r) v += fmaxf(acc[jj][r] + bias, 0.f);
    v += __shfl_down(v, 32);
    v += __shfl_down(v, 16);
    if (lane < 16) psum[n] = scrub(v);
  }
  __syncthreads();

  // ---- linear classifier epilogue: out[b][c] += (psum . cls_w[c]) / SEQ
  {
    float pn = psum[tid];                // tid = n, all 256 covered
    #pragma unroll
    for (int c = 0; c < NCLS; ++c){
      float t = pn * cls_w[c*HID + tid];
      for (int off = 32; off; off >>= 1) t += __shfl_down(t, off);
      if (lane == 0) oacc[wv][c] = t;
    }
    __syncthreads();
    if (tid < NCLS){
      float s = oacc[0][tid] + oacc[1][tid] + oacc[2][tid] + oacc[3][tid];
      atomicAdd(&out[b*NCLS + tid], scrub(s * (1.0f/SEQ)));
    }
    if ((blockIdx.x & 127) == 0 && tid < NCLS)     // once per batch: bias
      atomicAdd(&out[b*NCLS + tid], cls_b[tid]);
  }
}

// ---------------------------------------------------------------------------
extern "C" void kernel_launch(void* const* d_in, const int* in_sizes, int n_in,
                              void* d_out, int out_size, void* d_ws, size_t ws_size,
                              hipStream_t stream) {
  const int*   tokens = (const int*)d_in[0];
  const int*   edges  = (const int*)d_in[2];
  const float* emb    = (const float*)d_in[3];
  const float* A_log  = (const float*)d_in[4];
  const float* B_w    = (const float*)d_in[5];
  const float* C_w    = (const float*)d_in[6];
  const float* D_skip = (const float*)d_in[7];
  const float* ln_g   = (const float*)d_in[8];
  const float* ln_b   = (const float*)d_in[9];
  const float* Wmsg   = (const float*)d_in[10];
  const float* Wupd   = (const float*)d_in[11];
  const float* Wupd_b = (const float*)d_in[12];
  const float* cls_w  = (const float*)d_in[13];
  const float* cls_b  = (const float*)d_in[14];
  float* out = (float*)d_out;

  // workspace layout (~10.4 MB; x_bf eliminated)
  char* ws = (char*)d_ws;
  float* c_tab = (float*)ws;  ws += 16*1024;                 // 4 KB used
  float* MT    = (float*)ws;  ws += (size_t)HID*EMBED*4;     // 128 KB
  short* Wcs   = (short*)ws;  ws += (size_t)HID*HID*2;       // 128 KB
  short* Bf    = (short*)ws;  ws += 16*1024;                 // 4 KB used
  char*  zbase = ws;
  int*   cnt   = (int*)ws;    ws += (size_t)NROW*4;          // 128 KB
  int*   ovf_cnt = (int*)ws;  ws += 64;
  int*   ovf   = (int*)ws;    ws += OVCAP*4;                 // 4 KB
  size_t zlen = (size_t)((char*)ws - zbase);
  unsigned short* bucket = (unsigned short*)ws; ws += (size_t)NROW*BCAP*2; // 2 MB
  short* h_bf  = (short*)ws;  ws += (size_t)NROW*EMBED*2;    // 8 MB

  hipMemsetAsync(zbase, 0, zlen, stream);
  hipMemsetAsync(out, 0, (size_t)B_SZ*NCLS*4, stream);
  hipLaunchKernelGGL(k_prep, dim3(PB_TOTAL), dim3(256), 0, stream,
                     A_log, B_w, Wmsg, Wupd, edges,
                     c_tab, Bf, MT, cnt, bucket, ovf_cnt, ovf);
  hipLaunchKernelGGL(k_ssm_fused, dim3(544), dim3(256), 0, stream,
                     tokens, emb, c_tab, C_w, D_skip, ln_g, ln_b, Bf, Wupd, MT,
                     (unsigned int*)h_bf, Wcs);
  hipLaunchKernelGGL(k_gupd, dim3(NROW/16), dim3(256), 0, stream,
                     h_bf, cnt, bucket, ovf_cnt, ovf, Wcs, Wupd_b,
                     cls_w, cls_b, out);
}

// Round 9
// 179.875 us; speedup vs baseline: 1.0781x; 1.0010x over previous
//
#include <hip/hip_runtime.h>

#define B_SZ   16
#define SEQ    2048
#define VOCAB  50257
#define EMBED  128
#define DSTATE 16
#define HID    256
#define NCLS   10
#define NEDGE  8192
#define KTR    64          // scan truncation: A<=0.55 -> A^64 < 2e-17
#define LN_EPS 1e-5f
#define NROW   (B_SZ*SEQ)  // 32768
#define BCAP   32          // bucket capacity per dst (Poisson lambda=4)
#define OVCAP  1024        // overflow fallback capacity

// k_prep phase block ranges (cast fused into k_ssm_fused r8; bucket moved
// to k_ssm_fused riders r9)
#define PB_PRECM  128                   // 256 hp, 2 per block
#define PB_CTAB   (PB_PRECM + 16)       // 16 d
#define PB_TOTAL  (PB_CTAB + 1)         // +1 precB

typedef float  f32x4 __attribute__((ext_vector_type(4)));
typedef short  s16x8 __attribute__((ext_vector_type(8)));

__device__ __forceinline__ float scrub(float x){
  return (x == x && fabsf(x) < 1e30f) ? x : 0.f;
}
// fp32 -> bf16 bits, round-to-nearest-even
__device__ __forceinline__ short f2b(float f){
  unsigned int u = __float_as_uint(f);
  unsigned int r = (u + 0x7fffu + ((u >> 16) & 1u)) >> 16;
  return (short)r;
}
__device__ __forceinline__ unsigned int pack2(float a, float b){
  return (unsigned int)(unsigned short)f2b(a)
       | ((unsigned int)(unsigned short)f2b(b) << 16);
}
__device__ __forceinline__ float lo2f(unsigned int v){ return __uint_as_float(v << 16); }
__device__ __forceinline__ float hi2f(unsigned int v){ return __uint_as_float(v & 0xffff0000u); }

// ---------------------------------------------------------------------------
// Prep kernel: precM + ctab + precB only (tiny, 145 blocks).
__global__ __launch_bounds__(256) void k_prep(
    const float* __restrict__ A_log, const float* __restrict__ B_w,
    const float* __restrict__ Wmsg, const float* __restrict__ Wupd,
    float* __restrict__ c_tab, short* __restrict__ Bf, float* __restrict__ MT){
  int bid = blockIdx.x, tid = threadIdx.x;
  if (bid < PB_PRECM){                           // ---- precM: 2 hp per block
    int hp = bid*2 + (tid >> 7);                 // 0..255
    int e  = tid & 127;
    const float* w2 = Wupd + (size_t)hp*384 + 128;
    float acc = 0.f;
    for (int h1 = 0; h1 < HID; ++h1)
      acc += Wmsg[h1*EMBED + e] * w2[h1];
    MT[(size_t)hp*EMBED + e] = scrub(acc);
  } else if (bid < PB_CTAB){                     // ---- ctab (wave 0 only)
    if (tid < 64){
      int d = bid - PB_PRECM, lane = tid;        // d = 0..15
      float a0 = scrub(expf(-expf(A_log[(2*lane+0)*DSTATE + d])));
      float a1 = scrub(expf(-expf(A_log[(2*lane+1)*DSTATE + d])));
      float p0 = 1.f, p1 = 1.f;
      for (int k = 0; k < KTR; ++k){
        float s = p0 + p1;
        for (int off = 32; off; off >>= 1) s += __shfl_down(s, off);
        if (lane == 0) c_tab[k*DSTATE + d] = scrub(s * (1.0f/128.0f));
        p0 *= a0; p1 *= a1;
      }
    }
  } else {                                       // ---- precB (256 slots)
    int idx = tid;
    int c = idx >> 6, lane = idx & 63;
    int n = lane & 15;
    int kb = c*32 + (lane >> 4)*8;
    short v[8];
    #pragma unroll
    for (int jj = 0; jj < 8; ++jj) v[jj] = f2b(B_w[(size_t)n*EMBED + kb + jj]);
    *(s16x8*)(Bf + (size_t)idx*8) = *(s16x8*)v;
  }
}

// ---------------------------------------------------------------------------
// Fused emb-cast + bproj(MFMA) + conv + ssm + LayerNorm.
//   blocks [0,512)    : 64 output rows each (r8 structure)
//   blocks [512,544)  : precW riders — combined weight into B-fragment order
//   blocks [544,1056) : bucket riders (r9) — output consumed only by k_gupd,
//                       so riding here hides the bucket phase in the SSM tail.
__global__ __launch_bounds__(256) void k_ssm_fused(
    const int* __restrict__ tokens, const float* __restrict__ emb,
    const float* __restrict__ c_tab,
    const float* __restrict__ C_w, const float* __restrict__ D_skip,
    const float* __restrict__ ln_g, const float* __restrict__ ln_b,
    const short* __restrict__ Bf, const float* __restrict__ Wupd,
    const float* __restrict__ MT, unsigned int* __restrict__ h_out,
    short* __restrict__ Wcs, const int* __restrict__ edges,
    int* __restrict__ cnt, unsigned short* __restrict__ bucket,
    int* __restrict__ ovf_cnt, int* __restrict__ ovf){
  __shared__ unsigned int xsh[128][68]; // 34.8 KB x-tile (bf16 pairs)
  __shared__ float bsh[128][18];        // stride 18: 2-way (free) banking
  __shared__ float msh[64][18];
  __shared__ float Ct[DSTATE][EMBED+2];
  __shared__ float csh[KTR][DSTATE];
  int bid = blockIdx.x, tid = threadIdx.x;

  if (bid >= 544){                      // ---- bucket rider blocks
    int eid = (bid-544)*256 + tid;      // = B_SZ*NEDGE exactly
    int b2 = eid >> 13, i = eid & (NEDGE-1);
    const int* ei = edges + (size_t)b2*2*NEDGE;
    int s = ei[i]         & (SEQ-1);
    int d = ei[NEDGE + i] & (SEQ-1);
    int gdst = (b2 << 11) | d;
    int slot = atomicAdd(&cnt[gdst], 1);
    if (slot < BCAP) bucket[(size_t)gdst*BCAP + slot] = (unsigned short)s;
    else {
      int o = atomicAdd(ovf_cnt, 1);
      if (o < OVCAP) ovf[o] = ((b2 << 11) | s) | (gdst << 16);
    }
    return;
  }

  if (bid >= 512){                      // ---- precW rider blocks
    int idx = (bid-512)*256 + tid;      // 8192 fragment slots
    int c    = idx >> 10;
    int rem  = idx & 1023;
    int j    = rem >> 6;
    int lane = rem & 63;
    int n  = j*16 + (lane & 15);
    int kb = c*32 + (lane >> 4)*8;
    short v[8];
    #pragma unroll
    for (int jj = 0; jj < 8; ++jj){
      int k = kb + jj;
      float val = (k < 128) ? Wupd[(size_t)n*384 + k] : MT[(size_t)n*EMBED + (k-128)];
      v[jj] = f2b(val);
    }
    *(s16x8*)(Wcs + (size_t)idx*8) = *(s16x8*)v;
    return;
  }

  int b  = bid >> 5;
  int t0 = (bid & 31) * 64;

  // ---- emb gather -> LDS x-tile (bit-identical pack2 path)
  {
    const int* tkb = tokens + b*SEQ;
    for (int i = 0; i < 16; ++i){
      int gid = i*256 + tid;            // 4096 = 128 rows x 32 chunks
      int lr = gid >> 5, ch = gid & 31;
      int t = t0 - 64 + lr;
      uint2 o; o.x = 0u; o.y = 0u;
      if (t >= 0){
        int tok = tkb[t];
        tok = tok < 0 ? 0 : (tok >= VOCAB ? VOCAB-1 : tok);
        float4 v = *(const float4*)(emb + (size_t)tok*EMBED + ch*4);
        o.x = pack2(v.x, v.y); o.y = pack2(v.z, v.w);
      }
      *(uint2*)&xsh[lr][ch*2] = o;
    }
  }
  for (int i = tid; i < DSTATE*EMBED; i += 256){
    int e = i >> 4, d = i & 15;         // coalesced read of C_w[e][d]
    Ct[d][e] = C_w[i];
  }
  for (int i = tid; i < KTR*DSTATE; i += 256)
    csh[i >> 4][i & 15] = c_tab[i];
  __syncthreads();

  int wv = tid >> 6, lane = tid & 63;
  int m = lane & 15, lg = lane >> 4;

  // ---- bproj via MFMA: 8 tiles x 16 rows covering t0-64 .. t0+63 (from LDS)
  const s16x8* Bp = (const s16x8*)Bf;
  #pragma unroll
  for (int tt = 0; tt < 2; ++tt){
    int tile = wv*2 + tt;               // 0..7
    int trow = t0 - 64 + tile*16;
    f32x4 acc = (f32x4){0.f,0.f,0.f,0.f};
    if (trow >= 0){
      const short* xrow = (const short*)&xsh[tile*16 + m][0] + lg*8;
      #pragma unroll
      for (int c = 0; c < 4; ++c){
        s16x8 a = *(const s16x8*)(xrow + c*32);
        acc = __builtin_amdgcn_mfma_f32_16x16x32_bf16(a, Bp[c*64 + lane], acc, 0, 0, 0);
      }
    }
    // C/D: col = lane&15 (=d), row = lg*4 + r
    #pragma unroll
    for (int r = 0; r < 4; ++r)
      bsh[tile*16 + lg*4 + r][m] = scrub(acc[r]);
  }
  __syncthreads();

  // ---- conv from LDS (taps in csh, uniform-address broadcast)
  {
    int d = tid & 15;
    #pragma unroll
    for (int it = 0; it < 4; ++it){
      int q = (tid + it*256) >> 4;      // 0..63
      int t = t0 + q;
      int base = 64 + q;
      int kmax = (t+1 < KTR) ? t+1 : KTR;
      float acc = 0.f;
      for (int k = 0; k < kmax; ++k) acc += csh[k][d] * bsh[base-k][d];
      msh[q][d] = scrub(acc);
    }
  }
  __syncthreads();

  // ---- ssm + LN: each wave 16 rows; x from LDS tile
  int e0 = lane*2;
  float2 dsk = *(const float2*)&D_skip[e0];
  float2 lgv = *(const float2*)&ln_g[e0];
  float2 lbv = *(const float2*)&ln_b[e0];
  for (int q = wv*16; q < wv*16+16; ++q){
    int row = b*SEQ + t0 + q;
    unsigned int xp = xsh[64 + q][lane];
    float x0 = lo2f(xp), x1 = hi2f(xp);
    float y0 = dsk.x*x0, y1 = dsk.y*x1;
    #pragma unroll
    for (int d = 0; d < DSTATE; ++d){
      float md = msh[q][d];             // wave-uniform -> LDS broadcast
      y0 += md * Ct[d][e0];
      y1 += md * Ct[d][e0+1];
    }
    y0 = scrub(y0); y1 = scrub(y1);
    float s = y0+y1, s2 = y0*y0 + y1*y1;
    for (int off = 32; off; off >>= 1){ s += __shfl_down(s,off); s2 += __shfl_down(s2,off); }
    s = __shfl(s, 0); s2 = __shfl(s2, 0);
    float mu  = s * (1.f/EMBED);
    float var = s2 * (1.f/EMBED) - mu*mu;
    float inv = rsqrtf(fmaxf(var, 0.f) + LN_EPS);
    float o0 = scrub(lgv.x*(y0-mu)*inv + lbv.x);
    float o1 = scrub(lgv.y*(y1-mu)*inv + lbv.y);
    h_out[(size_t)row*(EMBED/2) + lane] = pack2(o0, o1);
  }
}

// ---------------------------------------------------------------------------
// Fused back half: gather + MFMA upd + relu + psum + classifier epilogue.
// r9: gather 2 rows per wave CONCURRENTLY (one per half-wave, 32 lanes x
// uint2 = same 256B coalesced txn) -> 8 independent loads in flight (was 4).
// Per-element accumulation stays in t-order -> bit-identical sums.
__global__ __launch_bounds__(256) void k_gupd(
    const short* __restrict__ h, const int* __restrict__ cnt,
    const unsigned short* __restrict__ bucket,
    const int* __restrict__ ovf_cnt, const int* __restrict__ ovf,
    const short* __restrict__ Wcs, const float* __restrict__ Wupd_b,
    const float* __restrict__ cls_w, const float* __restrict__ cls_b,
    float* __restrict__ out){
  __shared__ unsigned int gsh[16][68];   // padded g tile (b128-friendly)
  __shared__ float psum[HID];            // per-block pooled partials
  __shared__ float oacc[4][NCLS];        // per-wave class partials
  int tid = threadIdx.x;
  int wv = tid >> 6, lane = tid & 63;
  int row0 = blockIdx.x * 16;
  int b = row0 >> 11;                    // 16 | 2048: block is batch-pure
  int m = lane & 15, lg = lane >> 4;

  // ---- gather: 2 rows per wave concurrently; 4-deep ILP per half-wave
  const unsigned int* hb  = (const unsigned int*)h + (size_t)b*SEQ*(EMBED/2);
  const unsigned int* h32 = (const unsigned int*)h;
  int on = *ovf_cnt; on = on > OVCAP ? OVCAP : on;   // ~always 0
  int hh = lane >> 5;                    // half-wave id 0/1
  int lw = lane & 31;                    // uint2 index within row
  for (int i = 0; i < 2; ++i){
    int rloc = wv*4 + i*2 + hh;          // 0..15
    int r = row0 + rloc;
    int n = cnt[r]; n = n > BCAP ? BCAP : n;
    const unsigned short* bk = bucket + (size_t)r*BCAP;
    float ax0=0.f, ay0=0.f, ax1=0.f, ay1=0.f;
    int t = 0;
    for (; t + 4 <= n; t += 4){          // 4 row-loads in flight per half
      ushort4 s4 = *(const ushort4*)(bk + t);
      uint2 v0 = *(const uint2*)&hb[(size_t)s4.x*(EMBED/2) + lw*2];
      uint2 v1 = *(const uint2*)&hb[(size_t)s4.y*(EMBED/2) + lw*2];
      uint2 v2 = *(const uint2*)&hb[(size_t)s4.z*(EMBED/2) + lw*2];
      uint2 v3 = *(const uint2*)&hb[(size_t)s4.w*(EMBED/2) + lw*2];
      ax0 += lo2f(v0.x); ay0 += hi2f(v0.x); ax1 += lo2f(v0.y); ay1 += hi2f(v0.y);
      ax0 += lo2f(v1.x); ay0 += hi2f(v1.x); ax1 += lo2f(v1.y); ay1 += hi2f(v1.y);
      ax0 += lo2f(v2.x); ay0 += hi2f(v2.x); ax1 += lo2f(v2.y); ay1 += hi2f(v2.y);
      ax0 += lo2f(v3.x); ay0 += hi2f(v3.x); ax1 += lo2f(v3.y); ay1 += hi2f(v3.y);
    }
    for (; t < n; ++t){                  // tail (<=3)
      uint2 v = *(const uint2*)&hb[(size_t)bk[t]*(EMBED/2) + lw*2];
      ax0 += lo2f(v.x); ay0 += hi2f(v.x); ax1 += lo2f(v.y); ay1 += hi2f(v.y);
    }
    for (int idx = 0; idx < on; ++idx){
      int pk = ovf[idx];
      if (((pk >> 16) & 0x7fff) == r){
        uint2 v = *(const uint2*)&h32[(size_t)(pk & 0xffff)*(EMBED/2) + lw*2];
        ax0 += lo2f(v.x); ay0 += hi2f(v.x); ax1 += lo2f(v.y); ay1 += hi2f(v.y);
      }
    }
    uint2 o; o.x = pack2(scrub(ax0), scrub(ay0));
    o.y = pack2(scrub(ax1), scrub(ay1));
    *(uint2*)&gsh[rloc][lw*2] = o;
  }
  __syncthreads();

  // ---- A-fragments: h from global (L2-hot), g from LDS (same bit path
  // as the old g_bf route: pack2 then fragment reinterpret)
  const short* hrow = h + (size_t)(row0+m)*EMBED + lg*8;
  s16x8 hfrag[4], gfrag[4];
  #pragma unroll
  for (int c = 0; c < 4; ++c){
    hfrag[c] = *(const s16x8*)(hrow + c*32);
    gfrag[c] = *(const s16x8*)&gsh[m][c*16 + lg*4];
  }

  // ---- MFMA: [h || g] @ Wcs^T; 4 waves split the 16 j-tiles (4 each)
  int j0 = wv*4;
  f32x4 acc[4];
  #pragma unroll
  for (int jj = 0; jj < 4; ++jj) acc[jj] = (f32x4){0.f,0.f,0.f,0.f};
  const s16x8* Bp = (const s16x8*)Wcs;
  #pragma unroll
  for (int c = 0; c < 8; ++c){
    s16x8 a = (c < 4) ? hfrag[c] : gfrag[c-4];
    #pragma unroll
    for (int jj = 0; jj < 4; ++jj){
      s16x8 bfr = Bp[(c*16 + j0 + jj)*64 + lane];
      acc[jj] = __builtin_amdgcn_mfma_f32_16x16x32_bf16(a, bfr, acc[jj], 0, 0, 0);
    }
  }

  // ---- relu + row-sum over this block's 16 rows -> psum[n] (disjoint n/wave)
  #pragma unroll
  for (int jj = 0; jj < 4; ++jj){
    int n = (j0 + jj)*16 + m;
    float bias = Wupd_b[n];
    float v = 0.f;
    #pragma unroll
    for (int r = 0; r < 4; ++r) v += fmaxf(acc[jj][r] + bias, 0.f);
    v += __shfl_down(v, 32);
    v += __shfl_down(v, 16);
    if (lane < 16) psum[n] = scrub(v);
  }
  __syncthreads();

  // ---- linear classifier epilogue: out[b][c] += (psum . cls_w[c]) / SEQ
  {
    float pn = psum[tid];                // tid = n, all 256 covered
    #pragma unroll
    for (int c = 0; c < NCLS; ++c){
      float t = pn * cls_w[c*HID + tid];
      for (int off = 32; off; off >>= 1) t += __shfl_down(t, off);
      if (lane == 0) oacc[wv][c] = t;
    }
    __syncthreads();
    if (tid < NCLS){
      float s = oacc[0][tid] + oacc[1][tid] + oacc[2][tid] + oacc[3][tid];
      atomicAdd(&out[b*NCLS + tid], scrub(s * (1.0f/SEQ)));
    }
    if ((blockIdx.x & 127) == 0 && tid < NCLS)     // once per batch: bias
      atomicAdd(&out[b*NCLS + tid], cls_b[tid]);
  }
}

// ---------------------------------------------------------------------------
extern "C" void kernel_launch(void* const* d_in, const int* in_sizes, int n_in,
                              void* d_out, int out_size, void* d_ws, size_t ws_size,
                              hipStream_t stream) {
  const int*   tokens = (const int*)d_in[0];
  const int*   edges  = (const int*)d_in[2];
  const float* emb    = (const float*)d_in[3];
  const float* A_log  = (const float*)d_in[4];
  const float* B_w    = (const float*)d_in[5];
  const float* C_w    = (const float*)d_in[6];
  const float* D_skip = (const float*)d_in[7];
  const float* ln_g   = (const float*)d_in[8];
  const float* ln_b   = (const float*)d_in[9];
  const float* Wmsg   = (const float*)d_in[10];
  const float* Wupd   = (const float*)d_in[11];
  const float* Wupd_b = (const float*)d_in[12];
  const float* cls_w  = (const float*)d_in[13];
  const float* cls_b  = (const float*)d_in[14];
  float* out = (float*)d_out;

  // workspace layout (~10.4 MB)
  char* ws = (char*)d_ws;
  float* c_tab = (float*)ws;  ws += 16*1024;                 // 4 KB used
  float* MT    = (float*)ws;  ws += (size_t)HID*EMBED*4;     // 128 KB
  short* Wcs   = (short*)ws;  ws += (size_t)HID*HID*2;       // 128 KB
  short* Bf    = (short*)ws;  ws += 16*1024;                 // 4 KB used
  char*  zbase = ws;
  int*   cnt   = (int*)ws;    ws += (size_t)NROW*4;          // 128 KB
  int*   ovf_cnt = (int*)ws;  ws += 64;
  int*   ovf   = (int*)ws;    ws += OVCAP*4;                 // 4 KB
  size_t zlen = (size_t)((char*)ws - zbase);
  unsigned short* bucket = (unsigned short*)ws; ws += (size_t)NROW*BCAP*2; // 2 MB
  short* h_bf  = (short*)ws;  ws += (size_t)NROW*EMBED*2;    // 8 MB

  hipMemsetAsync(zbase, 0, zlen, stream);
  hipMemsetAsync(out, 0, (size_t)B_SZ*NCLS*4, stream);
  hipLaunchKernelGGL(k_prep, dim3(PB_TOTAL), dim3(256), 0, stream,
                     A_log, B_w, Wmsg, Wupd, c_tab, Bf, MT);
  hipLaunchKernelGGL(k_ssm_fused, dim3(1056), dim3(256), 0, stream,
                     tokens, emb, c_tab, C_w, D_skip, ln_g, ln_b, Bf, Wupd, MT,
                     (unsigned int*)h_bf, Wcs, edges, cnt, bucket, ovf_cnt, ovf);
  hipLaunchKernelGGL(k_gupd, dim3(NROW/16), dim3(256), 0, stream,
                     h_bf, cnt, bucket, ovf_cnt, ovf, Wcs, Wupd_b,
                     cls_w, cls_b, out);
}

// Round 10
// 175.674 us; speedup vs baseline: 1.1039x; 1.0239x over previous
//
#include <hip/hip_runtime.h>

#define B_SZ   16
#define SEQ    2048
#define VOCAB  50257
#define EMBED  128
#define DSTATE 16
#define HID    256
#define NCLS   10
#define NEDGE  8192
#define KTR    64          // scan truncation: A<=0.55 -> A^64 < 2e-17
#define LN_EPS 1e-5f
#define NROW   (B_SZ*SEQ)  // 32768
#define BCAP   32          // bucket capacity per dst (Poisson lambda=4)
#define OVCAP  1024        // overflow fallback capacity

// k_prep phase block ranges
#define PB_PRECM  128                   // 256 hp, 2 per block
#define PB_CTAB   (PB_PRECM + 16)       // 16 d
#define PB_PRECB  (PB_CTAB + 1)         // +1 precB          = 145
#define PB_ZNINT  33808                 // cnt(32768)+ovf_cnt(16)+ovf(1024)
#define PB_ZBLK   34                    // ceil(33808/1024)
#define PB_ZOUT   (PB_PRECB + PB_ZBLK)  // 179: zero out[160]
#define PB_TOTAL  (PB_ZOUT + 1)         // 180

// k_ssm_fused block ranges
#define SSM_MAIN  1024                  // 16 batches x 64 tiles of 32 rows
#define SSM_PRECW (SSM_MAIN + 32)       // 1056
#define SSM_TOTAL (SSM_PRECW + 512)     // 1568 (bucket riders)

typedef float  f32x4 __attribute__((ext_vector_type(4)));
typedef short  s16x8 __attribute__((ext_vector_type(8)));

__device__ __forceinline__ float scrub(float x){
  return (x == x && fabsf(x) < 1e30f) ? x : 0.f;
}
// fp32 -> bf16 bits, round-to-nearest-even
__device__ __forceinline__ short f2b(float f){
  unsigned int u = __float_as_uint(f);
  unsigned int r = (u + 0x7fffu + ((u >> 16) & 1u)) >> 16;
  return (short)r;
}
__device__ __forceinline__ unsigned int pack2(float a, float b){
  return (unsigned int)(unsigned short)f2b(a)
       | ((unsigned int)(unsigned short)f2b(b) << 16);
}
__device__ __forceinline__ float lo2f(unsigned int v){ return __uint_as_float(v << 16); }
__device__ __forceinline__ float hi2f(unsigned int v){ return __uint_as_float(v & 0xffff0000u); }

// ---------------------------------------------------------------------------
// Prep kernel: precM + ctab + precB + workspace/out zeroing riders
// (zeroing folded here r10 — k_prep precedes all consumers in stream order).
__global__ __launch_bounds__(256) void k_prep(
    const float* __restrict__ A_log, const float* __restrict__ B_w,
    const float* __restrict__ Wmsg, const float* __restrict__ Wupd,
    float* __restrict__ c_tab, short* __restrict__ Bf, float* __restrict__ MT,
    int* __restrict__ cnt, float* __restrict__ out){
  int bid = blockIdx.x, tid = threadIdx.x;
  if (bid < PB_PRECM){                           // ---- precM: 2 hp per block
    int hp = bid*2 + (tid >> 7);                 // 0..255
    int e  = tid & 127;
    const float* w2 = Wupd + (size_t)hp*384 + 128;
    float acc = 0.f;
    for (int h1 = 0; h1 < HID; ++h1)
      acc += Wmsg[h1*EMBED + e] * w2[h1];
    MT[(size_t)hp*EMBED + e] = scrub(acc);
  } else if (bid < PB_CTAB){                     // ---- ctab (wave 0 only)
    if (tid < 64){
      int d = bid - PB_PRECM, lane = tid;        // d = 0..15
      float a0 = scrub(expf(-expf(A_log[(2*lane+0)*DSTATE + d])));
      float a1 = scrub(expf(-expf(A_log[(2*lane+1)*DSTATE + d])));
      float p0 = 1.f, p1 = 1.f;
      for (int k = 0; k < KTR; ++k){
        float s = p0 + p1;
        for (int off = 32; off; off >>= 1) s += __shfl_down(s, off);
        if (lane == 0) c_tab[k*DSTATE + d] = scrub(s * (1.0f/128.0f));
        p0 *= a0; p1 *= a1;
      }
    }
  } else if (bid < PB_PRECB){                    // ---- precB (256 slots)
    int idx = tid;
    int c = idx >> 6, lane = idx & 63;
    int n = lane & 15;
    int kb = c*32 + (lane >> 4)*8;
    short v[8];
    #pragma unroll
    for (int jj = 0; jj < 8; ++jj) v[jj] = f2b(B_w[(size_t)n*EMBED + kb + jj]);
    *(s16x8*)(Bf + (size_t)idx*8) = *(s16x8*)v;
  } else if (bid < PB_ZOUT){                     // ---- zero cnt/ovf_cnt/ovf
    int idx4 = (bid-PB_PRECB)*1024 + tid*4;      // 16B-aligned int offset
    if (idx4 < PB_ZNINT){
      uint4 z; z.x = z.y = z.z = z.w = 0u;
      *(uint4*)&cnt[idx4] = z;
    }
  } else {                                       // ---- zero out[160]
    if (tid < B_SZ*NCLS) out[tid] = 0.f;
  }
}

// ---------------------------------------------------------------------------
// Fused emb-cast + bproj(MFMA) + conv + ssm + LayerNorm.
//   r10 occupancy redesign: 32-row output tiles, grid 1024 main blocks,
//   LDS 61->39 KB (Ct moved to registers) -> 4 blocks/CU (was 2).
//   blocks [0,1024)     : 32 output rows each (96-row x-tile incl. halo)
//   blocks [1024,1056)  : precW riders — combined weight in B-fragment order
//   blocks [1056,1568)  : bucket riders (consumed only by k_gupd)
__global__ __launch_bounds__(256) void k_ssm_fused(
    const int* __restrict__ tokens, const float* __restrict__ emb,
    const float* __restrict__ c_tab,
    const float* __restrict__ C_w, const float* __restrict__ D_skip,
    const float* __restrict__ ln_g, const float* __restrict__ ln_b,
    const short* __restrict__ Bf, const float* __restrict__ Wupd,
    const float* __restrict__ MT, unsigned int* __restrict__ h_out,
    short* __restrict__ Wcs, const int* __restrict__ edges,
    int* __restrict__ cnt, unsigned short* __restrict__ bucket,
    int* __restrict__ ovf_cnt, int* __restrict__ ovf){
  __shared__ unsigned int xsh[96][68];  // 26.1 KB x-tile (bf16 pairs)
  __shared__ float bsh[96][18];         // 6.75 KB; stride 18: 2-way (free)
  __shared__ float msh[32][18];         // 2.25 KB
  __shared__ float csh[KTR][DSTATE];    // 4 KB
  int bid = blockIdx.x, tid = threadIdx.x;

  if (bid >= SSM_PRECW){                // ---- bucket rider blocks
    int eid = (bid-SSM_PRECW)*256 + tid; // = B_SZ*NEDGE exactly
    int b2 = eid >> 13, i = eid & (NEDGE-1);
    const int* ei = edges + (size_t)b2*2*NEDGE;
    int s = ei[i]         & (SEQ-1);
    int d = ei[NEDGE + i] & (SEQ-1);
    int gdst = (b2 << 11) | d;
    int slot = atomicAdd(&cnt[gdst], 1);
    if (slot < BCAP) bucket[(size_t)gdst*BCAP + slot] = (unsigned short)s;
    else {
      int o = atomicAdd(ovf_cnt, 1);
      if (o < OVCAP) ovf[o] = ((b2 << 11) | s) | (gdst << 16);
    }
    return;
  }

  if (bid >= SSM_MAIN){                 // ---- precW rider blocks
    int idx = (bid-SSM_MAIN)*256 + tid; // 8192 fragment slots
    int c    = idx >> 10;
    int rem  = idx & 1023;
    int j    = rem >> 6;
    int lane = rem & 63;
    int n  = j*16 + (lane & 15);
    int kb = c*32 + (lane >> 4)*8;
    short v[8];
    #pragma unroll
    for (int jj = 0; jj < 8; ++jj){
      int k = kb + jj;
      float val = (k < 128) ? Wupd[(size_t)n*384 + k] : MT[(size_t)n*EMBED + (k-128)];
      v[jj] = f2b(val);
    }
    *(s16x8*)(Wcs + (size_t)idx*8) = *(s16x8*)v;
    return;
  }

  int b  = bid >> 6;                    // 64 blocks per batch
  int t0 = (bid & 63) * 32;
  int wv = tid >> 6, lane = tid & 63;
  int m = lane & 15, lg = lane >> 4;

  // ---- emb gather -> LDS x-tile: 96 rows (t0-64 .. t0+31), bit-identical
  {
    const int* tkb = tokens + b*SEQ;
    #pragma unroll
    for (int i = 0; i < 12; ++i){
      int gid = i*256 + tid;            // 3072 = 96 rows x 32 chunks
      int lr = gid >> 5, ch = gid & 31;
      int t = t0 - 64 + lr;
      uint2 o; o.x = 0u; o.y = 0u;
      if (t >= 0){
        int tok = tkb[t];
        tok = tok < 0 ? 0 : (tok >= VOCAB ? VOCAB-1 : tok);
        float4 v = *(const float4*)(emb + (size_t)tok*EMBED + ch*4);
        o.x = pack2(v.x, v.y); o.y = pack2(v.z, v.w);
      }
      *(uint2*)&xsh[lr][ch*2] = o;
    }
  }
  for (int i = tid; i < KTR*DSTATE; i += 256)
    csh[i >> 4][i & 15] = c_tab[i];

  // ---- C_w -> registers (32/lane): lane owns e0=lane*2, e0+1; contiguous
  int e0 = lane*2;
  float ct0[DSTATE], ct1[DSTATE];
  {
    const float4* c0 = (const float4*)(C_w + (size_t)e0*DSTATE);
    const float4* c1 = (const float4*)(C_w + (size_t)(e0+1)*DSTATE);
    #pragma unroll
    for (int i = 0; i < 4; ++i){
      float4 v0 = c0[i], v1 = c1[i];
      ct0[i*4+0]=v0.x; ct0[i*4+1]=v0.y; ct0[i*4+2]=v0.z; ct0[i*4+3]=v0.w;
      ct1[i*4+0]=v1.x; ct1[i*4+1]=v1.y; ct1[i*4+2]=v1.z; ct1[i*4+3]=v1.w;
    }
  }
  __syncthreads();

  // ---- bproj via MFMA: 6 tiles x 16 rows covering t0-64 .. t0+31 (from LDS)
  const s16x8* Bp = (const s16x8*)Bf;
  #pragma unroll
  for (int tt = 0; tt < 2; ++tt){
    int tile = wv*2 + tt;               // 0..7, use 0..5
    if (tile < 6){
      int trow = t0 - 64 + tile*16;
      f32x4 acc = (f32x4){0.f,0.f,0.f,0.f};
      if (trow >= 0){
        const short* xrow = (const short*)&xsh[tile*16 + m][0] + lg*8;
        #pragma unroll
        for (int c = 0; c < 4; ++c){
          s16x8 a = *(const s16x8*)(xrow + c*32);
          acc = __builtin_amdgcn_mfma_f32_16x16x32_bf16(a, Bp[c*64 + lane], acc, 0, 0, 0);
        }
      }
      // C/D: col = lane&15 (=d), row = lg*4 + r
      #pragma unroll
      for (int r = 0; r < 4; ++r)
        bsh[tile*16 + lg*4 + r][m] = scrub(acc[r]);
    }
  }
  __syncthreads();

  // ---- conv from LDS (taps in csh, uniform-address broadcast)
  {
    int d = tid & 15;
    #pragma unroll
    for (int it = 0; it < 2; ++it){
      int q = (tid + it*256) >> 4;      // 0..31
      int t = t0 + q;
      int base = 64 + q;
      int kmax = (t+1 < KTR) ? t+1 : KTR;
      float acc = 0.f;
      for (int k = 0; k < kmax; ++k) acc += csh[k][d] * bsh[base-k][d];
      msh[q][d] = scrub(acc);
    }
  }
  __syncthreads();

  // ---- ssm + LN: each wave 8 rows; x from LDS, C from registers
  float2 dsk = *(const float2*)&D_skip[e0];
  float2 lgv = *(const float2*)&ln_g[e0];
  float2 lbv = *(const float2*)&ln_b[e0];
  for (int q = wv*8; q < wv*8+8; ++q){
    int row = b*SEQ + t0 + q;
    unsigned int xp = xsh[64 + q][lane];
    float x0 = lo2f(xp), x1 = hi2f(xp);
    float y0 = dsk.x*x0, y1 = dsk.y*x1;
    #pragma unroll
    for (int d = 0; d < DSTATE; ++d){
      float md = msh[q][d];             // wave-uniform -> LDS broadcast
      y0 += md * ct0[d];
      y1 += md * ct1[d];
    }
    y0 = scrub(y0); y1 = scrub(y1);
    float s = y0+y1, s2 = y0*y0 + y1*y1;
    for (int off = 32; off; off >>= 1){ s += __shfl_down(s,off); s2 += __shfl_down(s2,off); }
    s = __shfl(s, 0); s2 = __shfl(s2, 0);
    float mu  = s * (1.f/EMBED);
    float var = s2 * (1.f/EMBED) - mu*mu;
    float inv = rsqrtf(fmaxf(var, 0.f) + LN_EPS);
    float o0 = scrub(lgv.x*(y0-mu)*inv + lbv.x);
    float o1 = scrub(lgv.y*(y1-mu)*inv + lbv.y);
    h_out[(size_t)row*(EMBED/2) + lane] = pack2(o0, o1);
  }
}

// ---------------------------------------------------------------------------
// Fused back half: gather + MFMA upd + relu + psum + classifier epilogue.
// (round-9 exact: half-wave gather, 8-deep ILP, 16 rows/block, grid 2048)
__global__ __launch_bounds__(256) void k_gupd(
    const short* __restrict__ h, const int* __restrict__ cnt,
    const unsigned short* __restrict__ bucket,
    const int* __restrict__ ovf_cnt, const int* __restrict__ ovf,
    const short* __restrict__ Wcs, const float* __restrict__ Wupd_b,
    const float* __restrict__ cls_w, const float* __restrict__ cls_b,
    float* __restrict__ out){
  __shared__ unsigned int gsh[16][68];   // padded g tile (b128-friendly)
  __shared__ float psum[HID];            // per-block pooled partials
  __shared__ float oacc[4][NCLS];        // per-wave class partials
  int tid = threadIdx.x;
  int wv = tid >> 6, lane = tid & 63;
  int row0 = blockIdx.x * 16;
  int b = row0 >> 11;                    // 16 | 2048: block is batch-pure
  int m = lane & 15, lg = lane >> 4;

  // ---- gather: 2 rows per wave concurrently; 4-deep ILP per half-wave
  const unsigned int* hb  = (const unsigned int*)h + (size_t)b*SEQ*(EMBED/2);
  const unsigned int* h32 = (const unsigned int*)h;
  int on = *ovf_cnt; on = on > OVCAP ? OVCAP : on;   // ~always 0
  int hh = lane >> 5;                    // half-wave id 0/1
  int lw = lane & 31;                    // uint2 index within row
  for (int i = 0; i < 2; ++i){
    int rloc = wv*4 + i*2 + hh;          // 0..15
    int r = row0 + rloc;
    int n = cnt[r]; n = n > BCAP ? BCAP : n;
    const unsigned short* bk = bucket + (size_t)r*BCAP;
    float ax0=0.f, ay0=0.f, ax1=0.f, ay1=0.f;
    int t = 0;
    for (; t + 4 <= n; t += 4){          // 4 row-loads in flight per half
      ushort4 s4 = *(const ushort4*)(bk + t);
      uint2 v0 = *(const uint2*)&hb[(size_t)s4.x*(EMBED/2) + lw*2];
      uint2 v1 = *(const uint2*)&hb[(size_t)s4.y*(EMBED/2) + lw*2];
      uint2 v2 = *(const uint2*)&hb[(size_t)s4.z*(EMBED/2) + lw*2];
      uint2 v3 = *(const uint2*)&hb[(size_t)s4.w*(EMBED/2) + lw*2];
      ax0 += lo2f(v0.x); ay0 += hi2f(v0.x); ax1 += lo2f(v0.y); ay1 += hi2f(v0.y);
      ax0 += lo2f(v1.x); ay0 += hi2f(v1.x); ax1 += lo2f(v1.y); ay1 += hi2f(v1.y);
      ax0 += lo2f(v2.x); ay0 += hi2f(v2.x); ax1 += lo2f(v2.y); ay1 += hi2f(v2.y);
      ax0 += lo2f(v3.x); ay0 += hi2f(v3.x); ax1 += lo2f(v3.y); ay1 += hi2f(v3.y);
    }
    for (; t < n; ++t){                  // tail (<=3)
      uint2 v = *(const uint2*)&hb[(size_t)bk[t]*(EMBED/2) + lw*2];
      ax0 += lo2f(v.x); ay0 += hi2f(v.x); ax1 += lo2f(v.y); ay1 += hi2f(v.y);
    }
    for (int idx = 0; idx < on; ++idx){
      int pk = ovf[idx];
      if (((pk >> 16) & 0x7fff) == r){
        uint2 v = *(const uint2*)&h32[(size_t)(pk & 0xffff)*(EMBED/2) + lw*2];
        ax0 += lo2f(v.x); ay0 += hi2f(v.x); ax1 += lo2f(v.y); ay1 += hi2f(v.y);
      }
    }
    uint2 o; o.x = pack2(scrub(ax0), scrub(ay0));
    o.y = pack2(scrub(ax1), scrub(ay1));
    *(uint2*)&gsh[rloc][lw*2] = o;
  }
  __syncthreads();

  // ---- A-fragments: h from global (L2-hot), g from LDS (same bit path
  // as the old g_bf route: pack2 then fragment reinterpret)
  const short* hrow = h + (size_t)(row0+m)*EMBED + lg*8;
  s16x8 hfrag[4], gfrag[4];
  #pragma unroll
  for (int c = 0; c < 4; ++c){
    hfrag[c] = *(const s16x8*)(hrow + c*32);
    gfrag[c] = *(const s16x8*)&gsh[m][c*16 + lg*4];
  }

  // ---- MFMA: [h || g] @ Wcs^T; 4 waves split the 16 j-tiles (4 each)
  int j0 = wv*4;
  f32x4 acc[4];
  #pragma unroll
  for (int jj = 0; jj < 4; ++jj) acc[jj] = (f32x4){0.f,0.f,0.f,0.f};
  const s16x8* Bp = (const s16x8*)Wcs;
  #pragma unroll
  for (int c = 0; c < 8; ++c){
    s16x8 a = (c < 4) ? hfrag[c] : gfrag[c-4];
    #pragma unroll
    for (int jj = 0; jj < 4; ++jj){
      s16x8 bfr = Bp[(c*16 + j0 + jj)*64 + lane];
      acc[jj] = __builtin_amdgcn_mfma_f32_16x16x32_bf16(a, bfr, acc[jj], 0, 0, 0);
    }
  }

  // ---- relu + row-sum over this block's 16 rows -> psum[n] (disjoint n/wave)
  #pragma unroll
  for (int jj = 0; jj < 4; ++jj){
    int n = (j0 + jj)*16 + m;
    float bias = Wupd_b[n];
    float v = 0.f;
    #pragma unroll
    for (int r = 0; r < 4; ++r) v += fmaxf(acc[jj][r] + bias, 0.f);
    v += __shfl_down(v, 32);
    v += __shfl_down(v, 16);
    if (lane < 16) psum[n] = scrub(v);
  }
  __syncthreads();

  // ---- linear classifier epilogue: out[b][c] += (psum . cls_w[c]) / SEQ
  {
    float pn = psum[tid];                // tid = n, all 256 covered
    #pragma unroll
    for (int c = 0; c < NCLS; ++c){
      float t = pn * cls_w[c*HID + tid];
      for (int off = 32; off; off >>= 1) t += __shfl_down(t, off);
      if (lane == 0) oacc[wv][c] = t;
    }
    __syncthreads();
    if (tid < NCLS){
      float s = oacc[0][tid] + oacc[1][tid] + oacc[2][tid] + oacc[3][tid];
      atomicAdd(&out[b*NCLS + tid], scrub(s * (1.0f/SEQ)));
    }
    if ((blockIdx.x & 127) == 0 && tid < NCLS)     // once per batch: bias
      atomicAdd(&out[b*NCLS + tid], cls_b[tid]);
  }
}

// ---------------------------------------------------------------------------
extern "C" void kernel_launch(void* const* d_in, const int* in_sizes, int n_in,
                              void* d_out, int out_size, void* d_ws, size_t ws_size,
                              hipStream_t stream) {
  const int*   tokens = (const int*)d_in[0];
  const int*   edges  = (const int*)d_in[2];
  const float* emb    = (const float*)d_in[3];
  const float* A_log  = (const float*)d_in[4];
  const float* B_w    = (const float*)d_in[5];
  const float* C_w    = (const float*)d_in[6];
  const float* D_skip = (const float*)d_in[7];
  const float* ln_g   = (const float*)d_in[8];
  const float* ln_b   = (const float*)d_in[9];
  const float* Wmsg   = (const float*)d_in[10];
  const float* Wupd   = (const float*)d_in[11];
  const float* Wupd_b = (const float*)d_in[12];
  const float* cls_w  = (const float*)d_in[13];
  const float* cls_b  = (const float*)d_in[14];
  float* out = (float*)d_out;

  // workspace layout (~10.4 MB)
  char* ws = (char*)d_ws;
  float* c_tab = (float*)ws;  ws += 16*1024;                 // 4 KB used
  float* MT    = (float*)ws;  ws += (size_t)HID*EMBED*4;     // 128 KB
  short* Wcs   = (short*)ws;  ws += (size_t)HID*HID*2;       // 128 KB
  short* Bf    = (short*)ws;  ws += 16*1024;                 // 4 KB used
  int*   cnt   = (int*)ws;    ws += (size_t)NROW*4;          // 128 KB
  int*   ovf_cnt = (int*)ws;  ws += 64;
  int*   ovf   = (int*)ws;    ws += OVCAP*4;                 // 4 KB
  unsigned short* bucket = (unsigned short*)ws; ws += (size_t)NROW*BCAP*2; // 2 MB
  short* h_bf  = (short*)ws;  ws += (size_t)NROW*EMBED*2;    // 8 MB

  // zeroing of cnt/ovf_cnt/ovf/out is done by k_prep rider blocks (r10)
  hipLaunchKernelGGL(k_prep, dim3(PB_TOTAL), dim3(256), 0, stream,
                     A_log, B_w, Wmsg, Wupd, c_tab, Bf, MT, cnt, out);
  hipLaunchKernelGGL(k_ssm_fused, dim3(SSM_TOTAL), dim3(256), 0, stream,
                     tokens, emb, c_tab, C_w, D_skip, ln_g, ln_b, Bf, Wupd, MT,
                     (unsigned int*)h_bf, Wcs, edges, cnt, bucket, ovf_cnt, ovf);
  hipLaunchKernelGGL(k_gupd, dim3(NROW/16), dim3(256), 0, stream,
                     h_bf, cnt, bucket, ovf_cnt, ovf, Wcs, Wupd_b,
                     cls_w, cls_b, out);
}

// Round 11
// 172.629 us; speedup vs baseline: 1.1234x; 1.0176x over previous
//
#include <hip/hip_runtime.h>

#define B_SZ   16
#define SEQ    2048
#define VOCAB  50257
#define EMBED  128
#define DSTATE 16
#define HID    256
#define NCLS   10
#define NEDGE  8192
#define KTR    64          // scan truncation: A<=0.55 -> A^64 < 2e-17
#define LN_EPS 1e-5f
#define NROW   (B_SZ*SEQ)  // 32768
#define BCAP   32          // bucket capacity per dst (Poisson lambda=4)
#define OVCAP  1024        // overflow fallback capacity

// k_prep phase block ranges
#define PB_PRECM  128                   // 256 hp, 2 per block
#define PB_CTAB   (PB_PRECM + 16)       // 16 d
#define PB_PRECB  (PB_CTAB + 1)         // +1 precB          = 145
#define PB_ZNINT  33808                 // cnt(32768)+ovf_cnt(16)+ovf(1024)
#define PB_ZBLK   34                    // ceil(33808/1024)
#define PB_ZOUT   (PB_PRECB + PB_ZBLK)  // 179: zero out[160]
#define PB_TOTAL  (PB_ZOUT + 1)         // 180

// k_ssm_fused block ranges
#define SSM_MAIN  1024                  // 16 batches x 64 tiles of 32 rows
#define SSM_PRECW (SSM_MAIN + 32)       // 1056
#define SSM_TOTAL (SSM_PRECW + 512)     // 1568 (bucket riders)

typedef float  f32x4 __attribute__((ext_vector_type(4)));
typedef short  s16x8 __attribute__((ext_vector_type(8)));

__device__ __forceinline__ float scrub(float x){
  return (x == x && fabsf(x) < 1e30f) ? x : 0.f;
}
// fp32 -> bf16 bits, round-to-nearest-even
__device__ __forceinline__ short f2b(float f){
  unsigned int u = __float_as_uint(f);
  unsigned int r = (u + 0x7fffu + ((u >> 16) & 1u)) >> 16;
  return (short)r;
}
__device__ __forceinline__ unsigned int pack2(float a, float b){
  return (unsigned int)(unsigned short)f2b(a)
       | ((unsigned int)(unsigned short)f2b(b) << 16);
}
__device__ __forceinline__ float lo2f(unsigned int v){ return __uint_as_float(v << 16); }
__device__ __forceinline__ float hi2f(unsigned int v){ return __uint_as_float(v & 0xffff0000u); }

// ---------------------------------------------------------------------------
// Prep kernel: precM + ctab + precB + workspace/out zeroing riders (r10).
__global__ __launch_bounds__(256) void k_prep(
    const float* __restrict__ A_log, const float* __restrict__ B_w,
    const float* __restrict__ Wmsg, const float* __restrict__ Wupd,
    float* __restrict__ c_tab, short* __restrict__ Bf, float* __restrict__ MT,
    int* __restrict__ cnt, float* __restrict__ out){
  int bid = blockIdx.x, tid = threadIdx.x;
  if (bid < PB_PRECM){                           // ---- precM: 2 hp per block
    int hp = bid*2 + (tid >> 7);                 // 0..255
    int e  = tid & 127;
    const float* w2 = Wupd + (size_t)hp*384 + 128;
    float acc = 0.f;
    for (int h1 = 0; h1 < HID; ++h1)
      acc += Wmsg[h1*EMBED + e] * w2[h1];
    MT[(size_t)hp*EMBED + e] = scrub(acc);
  } else if (bid < PB_CTAB){                     // ---- ctab (wave 0 only)
    if (tid < 64){
      int d = bid - PB_PRECM, lane = tid;        // d = 0..15
      float a0 = scrub(expf(-expf(A_log[(2*lane+0)*DSTATE + d])));
      float a1 = scrub(expf(-expf(A_log[(2*lane+1)*DSTATE + d])));
      float p0 = 1.f, p1 = 1.f;
      for (int k = 0; k < KTR; ++k){
        float s = p0 + p1;
        for (int off = 32; off; off >>= 1) s += __shfl_down(s, off);
        if (lane == 0) c_tab[k*DSTATE + d] = scrub(s * (1.0f/128.0f));
        p0 *= a0; p1 *= a1;
      }
    }
  } else if (bid < PB_PRECB){                    // ---- precB (256 slots)
    int idx = tid;
    int c = idx >> 6, lane = idx & 63;
    int n = lane & 15;
    int kb = c*32 + (lane >> 4)*8;
    short v[8];
    #pragma unroll
    for (int jj = 0; jj < 8; ++jj) v[jj] = f2b(B_w[(size_t)n*EMBED + kb + jj]);
    *(s16x8*)(Bf + (size_t)idx*8) = *(s16x8*)v;
  } else if (bid < PB_ZOUT){                     // ---- zero cnt/ovf_cnt/ovf
    int idx4 = (bid-PB_PRECB)*1024 + tid*4;      // 16B-aligned int offset
    if (idx4 < PB_ZNINT){
      uint4 z; z.x = z.y = z.z = z.w = 0u;
      *(uint4*)&cnt[idx4] = z;
    }
  } else {                                       // ---- zero out[160]
    if (tid < B_SZ*NCLS) out[tid] = 0.f;
  }
}

// ---------------------------------------------------------------------------
// Fused emb-cast + bproj(MFMA) + conv + ssm + LayerNorm. (r10 exact)
//   blocks [0,1024)     : 32 output rows each (96-row x-tile incl. halo)
//   blocks [1024,1056)  : precW riders — combined weight in B-fragment order
//   blocks [1056,1568)  : bucket riders (consumed only by k_gupd)
__global__ __launch_bounds__(256) void k_ssm_fused(
    const int* __restrict__ tokens, const float* __restrict__ emb,
    const float* __restrict__ c_tab,
    const float* __restrict__ C_w, const float* __restrict__ D_skip,
    const float* __restrict__ ln_g, const float* __restrict__ ln_b,
    const short* __restrict__ Bf, const float* __restrict__ Wupd,
    const float* __restrict__ MT, unsigned int* __restrict__ h_out,
    short* __restrict__ Wcs, const int* __restrict__ edges,
    int* __restrict__ cnt, unsigned short* __restrict__ bucket,
    int* __restrict__ ovf_cnt, int* __restrict__ ovf){
  __shared__ unsigned int xsh[96][68];  // 26.1 KB x-tile (bf16 pairs)
  __shared__ float bsh[96][18];         // 6.75 KB; stride 18: 2-way (free)
  __shared__ float msh[32][18];         // 2.25 KB
  __shared__ float csh[KTR][DSTATE];    // 4 KB
  int bid = blockIdx.x, tid = threadIdx.x;

  if (bid >= SSM_PRECW){                // ---- bucket rider blocks
    int eid = (bid-SSM_PRECW)*256 + tid; // = B_SZ*NEDGE exactly
    int b2 = eid >> 13, i = eid & (NEDGE-1);
    const int* ei = edges + (size_t)b2*2*NEDGE;
    int s = ei[i]         & (SEQ-1);
    int d = ei[NEDGE + i] & (SEQ-1);
    int gdst = (b2 << 11) | d;
    int slot = atomicAdd(&cnt[gdst], 1);
    if (slot < BCAP) bucket[(size_t)gdst*BCAP + slot] = (unsigned short)s;
    else {
      int o = atomicAdd(ovf_cnt, 1);
      if (o < OVCAP) ovf[o] = ((b2 << 11) | s) | (gdst << 16);
    }
    return;
  }

  if (bid >= SSM_MAIN){                 // ---- precW rider blocks
    int idx = (bid-SSM_MAIN)*256 + tid; // 8192 fragment slots
    int c    = idx >> 10;
    int rem  = idx & 1023;
    int j    = rem >> 6;
    int lane = rem & 63;
    int n  = j*16 + (lane & 15);
    int kb = c*32 + (lane >> 4)*8;
    short v[8];
    #pragma unroll
    for (int jj = 0; jj < 8; ++jj){
      int k = kb + jj;
      float val = (k < 128) ? Wupd[(size_t)n*384 + k] : MT[(size_t)n*EMBED + (k-128)];
      v[jj] = f2b(val);
    }
    *(s16x8*)(Wcs + (size_t)idx*8) = *(s16x8*)v;
    return;
  }

  int b  = bid >> 6;                    // 64 blocks per batch
  int t0 = (bid & 63) * 32;
  int wv = tid >> 6, lane = tid & 63;
  int m = lane & 15, lg = lane >> 4;

  // ---- emb gather -> LDS x-tile: 96 rows (t0-64 .. t0+31), bit-identical
  {
    const int* tkb = tokens + b*SEQ;
    #pragma unroll
    for (int i = 0; i < 12; ++i){
      int gid = i*256 + tid;            // 3072 = 96 rows x 32 chunks
      int lr = gid >> 5, ch = gid & 31;
      int t = t0 - 64 + lr;
      uint2 o; o.x = 0u; o.y = 0u;
      if (t >= 0){
        int tok = tkb[t];
        tok = tok < 0 ? 0 : (tok >= VOCAB ? VOCAB-1 : tok);
        float4 v = *(const float4*)(emb + (size_t)tok*EMBED + ch*4);
        o.x = pack2(v.x, v.y); o.y = pack2(v.z, v.w);
      }
      *(uint2*)&xsh[lr][ch*2] = o;
    }
  }
  for (int i = tid; i < KTR*DSTATE; i += 256)
    csh[i >> 4][i & 15] = c_tab[i];

  // ---- C_w -> registers (32/lane): lane owns e0=lane*2, e0+1; contiguous
  int e0 = lane*2;
  float ct0[DSTATE], ct1[DSTATE];
  {
    const float4* c0 = (const float4*)(C_w + (size_t)e0*DSTATE);
    const float4* c1 = (const float4*)(C_w + (size_t)(e0+1)*DSTATE);
    #pragma unroll
    for (int i = 0; i < 4; ++i){
      float4 v0 = c0[i], v1 = c1[i];
      ct0[i*4+0]=v0.x; ct0[i*4+1]=v0.y; ct0[i*4+2]=v0.z; ct0[i*4+3]=v0.w;
      ct1[i*4+0]=v1.x; ct1[i*4+1]=v1.y; ct1[i*4+2]=v1.z; ct1[i*4+3]=v1.w;
    }
  }
  __syncthreads();

  // ---- bproj via MFMA: 6 tiles x 16 rows covering t0-64 .. t0+31 (from LDS)
  const s16x8* Bp = (const s16x8*)Bf;
  #pragma unroll
  for (int tt = 0; tt < 2; ++tt){
    int tile = wv*2 + tt;               // 0..7, use 0..5
    if (tile < 6){
      int trow = t0 - 64 + tile*16;
      f32x4 acc = (f32x4){0.f,0.f,0.f,0.f};
      if (trow >= 0){
        const short* xrow = (const short*)&xsh[tile*16 + m][0] + lg*8;
        #pragma unroll
        for (int c = 0; c < 4; ++c){
          s16x8 a = *(const s16x8*)(xrow + c*32);
          acc = __builtin_amdgcn_mfma_f32_16x16x32_bf16(a, Bp[c*64 + lane], acc, 0, 0, 0);
        }
      }
      // C/D: col = lane&15 (=d), row = lg*4 + r
      #pragma unroll
      for (int r = 0; r < 4; ++r)
        bsh[tile*16 + lg*4 + r][m] = scrub(acc[r]);
    }
  }
  __syncthreads();

  // ---- conv from LDS (taps in csh, uniform-address broadcast)
  {
    int d = tid & 15;
    #pragma unroll
    for (int it = 0; it < 2; ++it){
      int q = (tid + it*256) >> 4;      // 0..31
      int t = t0 + q;
      int base = 64 + q;
      int kmax = (t+1 < KTR) ? t+1 : KTR;
      float acc = 0.f;
      for (int k = 0; k < kmax; ++k) acc += csh[k][d] * bsh[base-k][d];
      msh[q][d] = scrub(acc);
    }
  }
  __syncthreads();

  // ---- ssm + LN: each wave 8 rows; x from LDS, C from registers
  float2 dsk = *(const float2*)&D_skip[e0];
  float2 lgv = *(const float2*)&ln_g[e0];
  float2 lbv = *(const float2*)&ln_b[e0];
  for (int q = wv*8; q < wv*8+8; ++q){
    int row = b*SEQ + t0 + q;
    unsigned int xp = xsh[64 + q][lane];
    float x0 = lo2f(xp), x1 = hi2f(xp);
    float y0 = dsk.x*x0, y1 = dsk.y*x1;
    #pragma unroll
    for (int d = 0; d < DSTATE; ++d){
      float md = msh[q][d];             // wave-uniform -> LDS broadcast
      y0 += md * ct0[d];
      y1 += md * ct1[d];
    }
    y0 = scrub(y0); y1 = scrub(y1);
    float s = y0+y1, s2 = y0*y0 + y1*y1;
    for (int off = 32; off; off >>= 1){ s += __shfl_down(s,off); s2 += __shfl_down(s2,off); }
    s = __shfl(s, 0); s2 = __shfl(s2, 0);
    float mu  = s * (1.f/EMBED);
    float var = s2 * (1.f/EMBED) - mu*mu;
    float inv = rsqrtf(fmaxf(var, 0.f) + LN_EPS);
    float o0 = scrub(lgv.x*(y0-mu)*inv + lbv.x);
    float o1 = scrub(lgv.y*(y1-mu)*inv + lbv.y);
    h_out[(size_t)row*(EMBED/2) + lane] = pack2(o0, o1);
  }
}

// ---------------------------------------------------------------------------
// Fused back half, r11: SOFTWARE-PIPELINED gather.
//   r6 counters: all pipes idle, gather {load->barrier->MFMA} fully serial.
//   New order: (1) issue first 4-deep batch of gather loads (guarded to row
//   0 when t>=n, accumulate-predicated), (2) h-part MFMAs c=0..3 (independent
//   of gather), (3) finish gather in original t-order + ovf, pack, barrier,
//   (4) g-part MFMAs c=4..7. Same values, same add order -> bit-identical.
__global__ __launch_bounds__(256) void k_gupd(
    const short* __restrict__ h, const int* __restrict__ cnt,
    const unsigned short* __restrict__ bucket,
    const int* __restrict__ ovf_cnt, const int* __restrict__ ovf,
    const short* __restrict__ Wcs, const float* __restrict__ Wupd_b,
    const float* __restrict__ cls_w, const float* __restrict__ cls_b,
    float* __restrict__ out){
  __shared__ unsigned int gsh[16][68];   // padded g tile (b128-friendly)
  __shared__ float psum[HID];            // per-block pooled partials
  __shared__ float oacc[4][NCLS];        // per-wave class partials
  int tid = threadIdx.x;
  int wv = tid >> 6, lane = tid & 63;
  int row0 = blockIdx.x * 16;
  int b = row0 >> 11;                    // 16 | 2048: block is batch-pure
  int m = lane & 15, lg = lane >> 4;

  const unsigned int* hb  = (const unsigned int*)h + (size_t)b*SEQ*(EMBED/2);
  const unsigned int* h32 = (const unsigned int*)h;
  int hh = lane >> 5;                    // half-wave id 0/1
  int lw = lane & 31;                    // uint2 index within row

  // ---- phase 1: issue first 4-deep gather batch for both rows (A: i=0, B: i=1)
  int rA = row0 + wv*4 + hh;
  int rB = row0 + wv*4 + 2 + hh;
  int nA = cnt[rA]; nA = nA > BCAP ? BCAP : nA;
  int nB = cnt[rB]; nB = nB > BCAP ? BCAP : nB;
  const unsigned short* bkA = bucket + (size_t)rA*BCAP;
  const unsigned short* bkB = bucket + (size_t)rB*BCAP;
  ushort4 sA = *(const ushort4*)bkA;     // BCAP=32 >= 4: always in-bounds
  ushort4 sB = *(const ushort4*)bkB;
  uint2 vA0 = *(const uint2*)&hb[(size_t)(0 < nA ? sA.x : 0)*(EMBED/2) + lw*2];
  uint2 vA1 = *(const uint2*)&hb[(size_t)(1 < nA ? sA.y : 0)*(EMBED/2) + lw*2];
  uint2 vA2 = *(const uint2*)&hb[(size_t)(2 < nA ? sA.z : 0)*(EMBED/2) + lw*2];
  uint2 vA3 = *(const uint2*)&hb[(size_t)(3 < nA ? sA.w : 0)*(EMBED/2) + lw*2];
  uint2 vB0 = *(const uint2*)&hb[(size_t)(0 < nB ? sB.x : 0)*(EMBED/2) + lw*2];
  uint2 vB1 = *(const uint2*)&hb[(size_t)(1 < nB ? sB.y : 0)*(EMBED/2) + lw*2];
  uint2 vB2 = *(const uint2*)&hb[(size_t)(2 < nB ? sB.z : 0)*(EMBED/2) + lw*2];
  uint2 vB3 = *(const uint2*)&hb[(size_t)(3 < nB ? sB.w : 0)*(EMBED/2) + lw*2];

  // ---- phase 2: h-part MFMAs (c=0..3) — independent of the gather
  const short* hrow = h + (size_t)(row0+m)*EMBED + lg*8;
  int j0 = wv*4;
  f32x4 acc[4];
  #pragma unroll
  for (int jj = 0; jj < 4; ++jj) acc[jj] = (f32x4){0.f,0.f,0.f,0.f};
  const s16x8* Bp = (const s16x8*)Wcs;
  #pragma unroll
  for (int c = 0; c < 4; ++c){
    s16x8 a = *(const s16x8*)(hrow + c*32);
    #pragma unroll
    for (int jj = 0; jj < 4; ++jj){
      s16x8 bfr = Bp[(c*16 + j0 + jj)*64 + lane];
      acc[jj] = __builtin_amdgcn_mfma_f32_16x16x32_bf16(a, bfr, acc[jj], 0, 0, 0);
    }
  }

  // ---- phase 3: finish gather (original t-order), pack to LDS, barrier
  int on = *ovf_cnt; on = on > OVCAP ? OVCAP : on;   // ~always 0
  {
    float ax0=0.f, ay0=0.f, ax1=0.f, ay1=0.f;
    if (0 < nA){ ax0 += lo2f(vA0.x); ay0 += hi2f(vA0.x); ax1 += lo2f(vA0.y); ay1 += hi2f(vA0.y); }
    if (1 < nA){ ax0 += lo2f(vA1.x); ay0 += hi2f(vA1.x); ax1 += lo2f(vA1.y); ay1 += hi2f(vA1.y); }
    if (2 < nA){ ax0 += lo2f(vA2.x); ay0 += hi2f(vA2.x); ax1 += lo2f(vA2.y); ay1 += hi2f(vA2.y); }
    if (3 < nA){ ax0 += lo2f(vA3.x); ay0 += hi2f(vA3.x); ax1 += lo2f(vA3.y); ay1 += hi2f(vA3.y); }
    for (int t = 4; t < nA; ++t){
      uint2 v = *(const uint2*)&hb[(size_t)bkA[t]*(EMBED/2) + lw*2];
      ax0 += lo2f(v.x); ay0 += hi2f(v.x); ax1 += lo2f(v.y); ay1 += hi2f(v.y);
    }
    for (int idx = 0; idx < on; ++idx){
      int pk = ovf[idx];
      if (((pk >> 16) & 0x7fff) == rA){
        uint2 v = *(const uint2*)&h32[(size_t)(pk & 0xffff)*(EMBED/2) + lw*2];
        ax0 += lo2f(v.x); ay0 += hi2f(v.x); ax1 += lo2f(v.y); ay1 += hi2f(v.y);
      }
    }
    uint2 o; o.x = pack2(scrub(ax0), scrub(ay0));
    o.y = pack2(scrub(ax1), scrub(ay1));
    *(uint2*)&gsh[rA - row0][lw*2] = o;
  }
  {
    float ax0=0.f, ay0=0.f, ax1=0.f, ay1=0.f;
    if (0 < nB){ ax0 += lo2f(vB0.x); ay0 += hi2f(vB0.x); ax1 += lo2f(vB0.y); ay1 += hi2f(vB0.y); }
    if (1 < nB){ ax0 += lo2f(vB1.x); ay0 += hi2f(vB1.x); ax1 += lo2f(vB1.y); ay1 += hi2f(vB1.y); }
    if (2 < nB){ ax0 += lo2f(vB2.x); ay0 += hi2f(vB2.x); ax1 += lo2f(vB2.y); ay1 += hi2f(vB2.y); }
    if (3 < nB){ ax0 += lo2f(vB3.x); ay0 += hi2f(vB3.x); ax1 += lo2f(vB3.y); ay1 += hi2f(vB3.y); }
    for (int t = 4; t < nB; ++t){
      uint2 v = *(const uint2*)&hb[(size_t)bkB[t]*(EMBED/2) + lw*2];
      ax0 += lo2f(v.x); ay0 += hi2f(v.x); ax1 += lo2f(v.y); ay1 += hi2f(v.y);
    }
    for (int idx = 0; idx < on; ++idx){
      int pk = ovf[idx];
      if (((pk >> 16) & 0x7fff) == rB){
        uint2 v = *(const uint2*)&h32[(size_t)(pk & 0xffff)*(EMBED/2) + lw*2];
        ax0 += lo2f(v.x); ay0 += hi2f(v.x); ax1 += lo2f(v.y); ay1 += hi2f(v.y);
      }
    }
    uint2 o; o.x = pack2(scrub(ax0), scrub(ay0));
    o.y = pack2(scrub(ax1), scrub(ay1));
    *(uint2*)&gsh[rB - row0][lw*2] = o;
  }
  __syncthreads();

  // ---- phase 4: g-part MFMAs (c=4..7) from LDS (same c-order as before)
  #pragma unroll
  for (int c = 4; c < 8; ++c){
    s16x8 a = *(const s16x8*)&gsh[m][(c-4)*16 + lg*4];
    #pragma unroll
    for (int jj = 0; jj < 4; ++jj){
      s16x8 bfr = Bp[(c*16 + j0 + jj)*64 + lane];
      acc[jj] = __builtin_amdgcn_mfma_f32_16x16x32_bf16(a, bfr, acc[jj], 0, 0, 0);
    }
  }

  // ---- relu + row-sum over this block's 16 rows -> psum[n] (disjoint n/wave)
  #pragma unroll
  for (int jj = 0; jj < 4; ++jj){
    int n = (j0 + jj)*16 + m;
    float bias = Wupd_b[n];
    float v = 0.f;
    #pragma unroll
    for (int r = 0; r < 4; ++r) v += fmaxf(acc[jj][r] + bias, 0.f);
    v += __shfl_down(v, 32);
    v += __shfl_down(v, 16);
    if (lane < 16) psum[n] = scrub(v);
  }
  __syncthreads();

  // ---- linear classifier epilogue: out[b][c] += (psum . cls_w[c]) / SEQ
  {
    float pn = psum[tid];                // tid = n, all 256 covered
    #pragma unroll
    for (int c = 0; c < NCLS; ++c){
      float t = pn * cls_w[c*HID + tid];
      for (int off = 32; off; off >>= 1) t += __shfl_down(t, off);
      if (lane == 0) oacc[wv][c] = t;
    }
    __syncthreads();
    if (tid < NCLS){
      float s = oacc[0][tid] + oacc[1][tid] + oacc[2][tid] + oacc[3][tid];
      atomicAdd(&out[b*NCLS + tid], scrub(s * (1.0f/SEQ)));
    }
    if ((blockIdx.x & 127) == 0 && tid < NCLS)     // once per batch: bias
      atomicAdd(&out[b*NCLS + tid], cls_b[tid]);
  }
}

// ---------------------------------------------------------------------------
extern "C" void kernel_launch(void* const* d_in, const int* in_sizes, int n_in,
                              void* d_out, int out_size, void* d_ws, size_t ws_size,
                              hipStream_t stream) {
  const int*   tokens = (const int*)d_in[0];
  const int*   edges  = (const int*)d_in[2];
  const float* emb    = (const float*)d_in[3];
  const float* A_log  = (const float*)d_in[4];
  const float* B_w    = (const float*)d_in[5];
  const float* C_w    = (const float*)d_in[6];
  const float* D_skip = (const float*)d_in[7];
  const float* ln_g   = (const float*)d_in[8];
  const float* ln_b   = (const float*)d_in[9];
  const float* Wmsg   = (const float*)d_in[10];
  const float* Wupd   = (const float*)d_in[11];
  const float* Wupd_b = (const float*)d_in[12];
  const float* cls_w  = (const float*)d_in[13];
  const float* cls_b  = (const float*)d_in[14];
  float* out = (float*)d_out;

  // workspace layout (~10.4 MB)
  char* ws = (char*)d_ws;
  float* c_tab = (float*)ws;  ws += 16*1024;                 // 4 KB used
  float* MT    = (float*)ws;  ws += (size_t)HID*EMBED*4;     // 128 KB
  short* Wcs   = (short*)ws;  ws += (size_t)HID*HID*2;       // 128 KB
  short* Bf    = (short*)ws;  ws += 16*1024;                 // 4 KB used
  int*   cnt   = (int*)ws;    ws += (size_t)NROW*4;          // 128 KB
  int*   ovf_cnt = (int*)ws;  ws += 64;
  int*   ovf   = (int*)ws;    ws += OVCAP*4;                 // 4 KB
  unsigned short* bucket = (unsigned short*)ws; ws += (size_t)NROW*BCAP*2; // 2 MB
  short* h_bf  = (short*)ws;  ws += (size_t)NROW*EMBED*2;    // 8 MB

  // zeroing of cnt/ovf_cnt/ovf/out is done by k_prep rider blocks (r10)
  hipLaunchKernelGGL(k_prep, dim3(PB_TOTAL), dim3(256), 0, stream,
                     A_log, B_w, Wmsg, Wupd, c_tab, Bf, MT, cnt, out);
  hipLaunchKernelGGL(k_ssm_fused, dim3(SSM_TOTAL), dim3(256), 0, stream,
                     tokens, emb, c_tab, C_w, D_skip, ln_g, ln_b, Bf, Wupd, MT,
                     (unsigned int*)h_bf, Wcs, edges, cnt, bucket, ovf_cnt, ovf);
  hipLaunchKernelGGL(k_gupd, dim3(NROW/16), dim3(256), 0, stream,
                     h_bf, cnt, bucket, ovf_cnt, ovf, Wcs, Wupd_b,
                     cls_w, cls_b, out);
}